// Round 5
// baseline (954.226 us; speedup 1.0000x reference)
//
#include <hip/hip_runtime.h>
#include <math.h>

namespace {

constexpr int NA  = 50000;
constexpr int NE  = 1600000;
constexpr int NM  = 500;
constexpr int H   = 128;
constexpr int G   = 50;
constexpr int L   = 6;
constexpr int TBL = 8192;
constexpr int PAD = 80;
constexpr float DMAX = 6.0f;

typedef _Float16 half8 __attribute__((ext_vector_type(8)));
typedef float f32x4 __attribute__((ext_vector_type(4)));
struct hpair { _Float16 x, y; };

__device__ __forceinline__ float sspf(float v) {
    return fmaxf(v, 0.0f) + log1pf(expf(-fabsf(v))) - 0.6931471805599453f;
}
__device__ __forceinline__ unsigned short f2h(float f) {
    _Float16 h = (_Float16)f;
    return __builtin_bit_cast(unsigned short, h);
}
__device__ __forceinline__ half8 cvt8(float4 a, float4 b) {
    half8 r;
    r[0] = (_Float16)a.x; r[1] = (_Float16)a.y; r[2] = (_Float16)a.z; r[3] = (_Float16)a.w;
    r[4] = (_Float16)b.x; r[5] = (_Float16)b.y; r[6] = (_Float16)b.z; r[7] = (_Float16)b.w;
    return r;
}
// B^T LDS granule offset with XOR swizzle for 128-u16 row pitch (G4)
__device__ __forceinline__ int bofs(int nrow, int g) {   // g = 16B granule 0..15
    int gs = (g & 8) | ((g ^ nrow) & 7);
    return nrow * 128 + gs * 8;
}
__device__ __forceinline__ void stageB(const unsigned short* __restrict__ Bt,
                                       unsigned short* Bs, int tid) {
    for (int i = tid; i < 2048; i += 256) {
        int row = i >> 4, g = i & 15;
        *(uint4*)&Bs[bofs(row, g)] = *(const uint4*)&Bt[i * 8];
    }
}

// ---------------- preprocessing: one-pass padded-CSR build ----------------

__global__ void edge_build(const float* __restrict__ pos, const int* __restrict__ ei,
                           int* __restrict__ counts, unsigned* __restrict__ meta) {
    int e = blockIdx.x * 256 + threadIdx.x;
    if (e >= NE) return;
    int s = ei[e], t = ei[NE + e];
    float dx = pos[3*s]   - pos[3*t];
    float dy = pos[3*s+1] - pos[3*t+1];
    float dz = pos[3*s+2] - pos[3*t+2];
    float d = sqrtf(dx*dx + dy*dy + dz*dz + 1e-12f);
    float u = d * ((float)(TBL - 1) / DMAX);
    if (u < (float)(TBL - 1)) {
        int idx = (int)(u + 0.5f);
        int r = atomicAdd(&counts[t], 1);
        if (r < PAD) meta[(size_t)t * PAD + r] = (unsigned)s | ((unsigned)idx << 16);
    }
}

__global__ void h_init(const int* __restrict__ z, const float* __restrict__ emb,
                       float* __restrict__ h) {
    int idx = blockIdx.x * 256 + threadIdx.x;
    if (idx >= NA * H) return;
    int i = idx >> 7, f = idx & 127;
    h[idx] = emb[(z[i] << 7) + f];
}

// f32 [K=128][N=128] -> f16 B^T [N][K]
__global__ void convT(const float* __restrict__ src, unsigned short* __restrict__ dst) {
    int m = blockIdx.y;
    int e = blockIdx.x * 256 + threadIdx.x;   // e = n*128 + k
    int n = e >> 7, k = e & 127;
    dst[(size_t)m * 16384 + e] = f2h(src[(size_t)m * 16384 + k * 128 + n]);
}

// f32 [L][50][128] -> f16 B^T [L][128][64] (zero-padded K)
__global__ void convT_pad(const float* __restrict__ src, unsigned short* __restrict__ dst) {
    int l = blockIdx.y;
    int i = blockIdx.x * 256 + threadIdx.x;   // i = n*64 + k
    int n = i >> 6, k = i & 63;
    float v = (k < G) ? src[(size_t)l * G * H + k * H + n] : 0.0f;
    dst[(size_t)l * 8192 + i] = f2h(v);
}

// ---------------- filter tables via MFMA: all L layers, one launch ----------------
// wtab[l][t][f] = (ssp(ea(d_t) @ iw1_l + b1) @ iw2_l + b2)[f] * C(d_t)

__global__ __launch_bounds__(256) void table_gemm(const unsigned short* __restrict__ iw1t,
                                                  const float* __restrict__ ib1,
                                                  const unsigned short* __restrict__ iw2t,
                                                  const float* __restrict__ ib2,
                                                  unsigned short* __restrict__ wtab) {
    __shared__ unsigned short Bs[16384];      // 32 KB
    __shared__ _Float16 Ts[64 * 136];         // 17 KB
    __shared__ _Float16 eaS[64][72];          // 9 KB
    int tid = threadIdx.x;
    int w = tid >> 6, lane = tid & 63, lr = lane & 15, lq = lane >> 4;
    int r0 = blockIdx.x * 64;
    int trow = w * 16;
    const float step  = DMAX / (float)(TBL - 1);
    const float sp    = 5.0f / 49.0f;
    const float coeff = -0.5f / (sp * sp);
    for (int i = tid; i < 64 * 64; i += 256) {
        int r = i >> 6, g = i & 63;
        float d = (float)(r0 + r) * step;
        float dd = d - (float)g * sp;
        eaS[r][g] = (_Float16)((g < G) ? expf(coeff * dd * dd) : 0.0f);
    }
    float Cj[4];
    #pragma unroll
    for (int j = 0; j < 4; ++j) {
        float d = (float)(r0 + trow + 4 * lq + j) * step;
        Cj[j] = 0.5f * (cosf(d * (3.14159265358979323846f / 5.0f)) + 1.0f);
    }
    __syncthreads();
    half8 af[2];
    #pragma unroll
    for (int ks = 0; ks < 2; ++ks)
        af[ks] = *(const half8*)&eaS[trow + lr][ks * 32 + lq * 8];

    for (int l = 0; l < L; ++l) {
        // stage iw1t_l [128 rows][64 u16] with 8-granule XOR swizzle
        for (int i = tid; i < 1024; i += 256) {
            int row = i >> 3, g = i & 7;
            int gs = (g ^ row) & 7;
            *(uint4*)&Bs[row * 64 + gs * 8] = *(const uint4*)&iw1t[(size_t)l * 8192 + i * 8];
        }
        __syncthreads();
        // pass A: t = ssp(ea @ iw1 + b1) -> Ts
        #pragma unroll
        for (int n = 0; n < 8; ++n) {
            f32x4 acc = {0.f, 0.f, 0.f, 0.f};
            #pragma unroll
            for (int ks = 0; ks < 2; ++ks) {
                int row = n * 16 + lr, g = ks * 4 + lq;
                half8 bf = *(const half8*)&Bs[row * 64 + ((g ^ row) & 7) * 8];
                acc = __builtin_amdgcn_mfma_f32_16x16x32_f16(af[ks], bf, acc, 0, 0, 0);
            }
            float b = ib1[l * H + n * 16 + lr];
            #pragma unroll
            for (int j = 0; j < 4; ++j)
                Ts[(trow + 4 * lq + j) * 136 + n * 16 + lr] = (_Float16)sspf(acc[j] + b);
        }
        __syncthreads();
        stageB(iw2t + (size_t)l * 16384, Bs, tid);
        half8 tf[4];
        #pragma unroll
        for (int ks = 0; ks < 4; ++ks)
            tf[ks] = *(const half8*)&Ts[(trow + lr) * 136 + ks * 32 + lq * 8];
        __syncthreads();
        // pass B: wtab = (t @ iw2 + b2) * C
        #pragma unroll
        for (int n = 0; n < 8; ++n) {
            f32x4 acc = {0.f, 0.f, 0.f, 0.f};
            #pragma unroll
            for (int ks = 0; ks < 4; ++ks) {
                half8 bf = *(const half8*)&Bs[bofs(n * 16 + lr, ks * 4 + lq)];
                acc = __builtin_amdgcn_mfma_f32_16x16x32_f16(tf[ks], bf, acc, 0, 0, 0);
            }
            float b = ib2[l * H + n * 16 + lr];
            #pragma unroll
            for (int j = 0; j < 4; ++j) {
                int row = r0 + trow + 4 * lq + j;
                wtab[(size_t)l * TBL * H + (size_t)row * H + n * 16 + lr] =
                    f2h((acc[j] + b) * Cj[j]);
            }
        }
        __syncthreads();
    }
}

// ---------------- standalone x = f16(h @ B)  (layer 0 only) ----------------

__global__ __launch_bounds__(256) void gemm_xonly(const float* __restrict__ A,
                                                  const unsigned short* __restrict__ Bt,
                                                  unsigned short* __restrict__ xout, int M) {
    __shared__ unsigned short Bs[16384];
    int tid = threadIdx.x;
    int w = tid >> 6, lane = tid & 63, lr = lane & 15, lq = lane >> 4;
    int r0 = blockIdx.x * 64 + w * 16;
    stageB(Bt, Bs, tid);
    const float* arow = A + (size_t)min(r0 + lr, M - 1) * H;
    half8 af[4];
    #pragma unroll
    for (int ks = 0; ks < 4; ++ks)
        af[ks] = cvt8(*(const float4*)(arow + ks * 32 + lq * 8),
                      *(const float4*)(arow + ks * 32 + lq * 8 + 4));
    __syncthreads();
    #pragma unroll
    for (int n = 0; n < 8; ++n) {
        f32x4 acc = {0.f, 0.f, 0.f, 0.f};
        #pragma unroll
        for (int ks = 0; ks < 4; ++ks) {
            half8 bf = *(const half8*)&Bs[bofs(n * 16 + lr, ks * 4 + lq)];
            acc = __builtin_amdgcn_mfma_f32_16x16x32_f16(af[ks], bf, acc, 0, 0, 0);
        }
        #pragma unroll
        for (int j = 0; j < 4; ++j) {
            int row = r0 + 4 * lq + j;
            if (row < M) xout[(size_t)row * H + n * 16 + lr] = f2h(acc[j]);
        }
    }
}

// ---------------- fused node update ----------------

template<int RES, int HASX, int AF16>
__global__ __launch_bounds__(256) void node_fused(const unsigned short* __restrict__ Ain16,
                                                  const float* __restrict__ Ain32,
                                                  const float* __restrict__ bias1,
                                                  const unsigned short* __restrict__ B1t,
                                                  const float* __restrict__ hres,
                                                  float* __restrict__ hout,
                                                  const float* __restrict__ bias2,
                                                  const unsigned short* __restrict__ B2t,
                                                  const unsigned short* __restrict__ B3t,
                                                  unsigned short* __restrict__ xout, int M) {
    __shared__ unsigned short Bs[16384];
    __shared__ _Float16 Ts[64 * 136];
    int tid = threadIdx.x;
    int w = tid >> 6, lane = tid & 63, lr = lane & 15, lq = lane >> 4;
    int r0 = blockIdx.x * 64 + w * 16;
    int trow = w * 16;

    stageB(B1t, Bs, tid);
    half8 af[4];
    if (AF16) {
        const unsigned short* arow = Ain16 + (size_t)min(r0 + lr, M - 1) * H;
        #pragma unroll
        for (int ks = 0; ks < 4; ++ks)
            af[ks] = *(const half8*)(arow + ks * 32 + lq * 8);
    } else {
        const float* arow = Ain32 + (size_t)min(r0 + lr, M - 1) * H;
        #pragma unroll
        for (int ks = 0; ks < 4; ++ks)
            af[ks] = cvt8(*(const float4*)(arow + ks * 32 + lq * 8),
                          *(const float4*)(arow + ks * 32 + lq * 8 + 4));
    }
    __syncthreads();

    #pragma unroll
    for (int n = 0; n < 8; ++n) {
        f32x4 acc = {0.f, 0.f, 0.f, 0.f};
        #pragma unroll
        for (int ks = 0; ks < 4; ++ks) {
            half8 bf = *(const half8*)&Bs[bofs(n * 16 + lr, ks * 4 + lq)];
            acc = __builtin_amdgcn_mfma_f32_16x16x32_f16(af[ks], bf, acc, 0, 0, 0);
        }
        float b = bias1[n * 16 + lr];
        #pragma unroll
        for (int j = 0; j < 4; ++j)
            Ts[(trow + 4 * lq + j) * 136 + n * 16 + lr] = (_Float16)sspf(acc[j] + b);
    }
    __syncthreads();
    stageB(B2t, Bs, tid);
    half8 tf[4];
    #pragma unroll
    for (int ks = 0; ks < 4; ++ks)
        tf[ks] = *(const half8*)&Ts[(trow + lr) * 136 + ks * 32 + lq * 8];
    __syncthreads();

    #pragma unroll
    for (int n = 0; n < 8; ++n) {
        f32x4 acc = {0.f, 0.f, 0.f, 0.f};
        #pragma unroll
        for (int ks = 0; ks < 4; ++ks) {
            half8 bf = *(const half8*)&Bs[bofs(n * 16 + lr, ks * 4 + lq)];
            acc = __builtin_amdgcn_mfma_f32_16x16x32_f16(tf[ks], bf, acc, 0, 0, 0);
        }
        float b = bias2[n * 16 + lr];
        #pragma unroll
        for (int j = 0; j < 4; ++j) {
            int row = r0 + 4 * lq + j;
            float v = acc[j] + b;
            if (RES) v += hres[(size_t)min(row, M - 1) * H + n * 16 + lr];
            if (row < M) hout[(size_t)row * H + n * 16 + lr] = v;
            if (HASX) Ts[(trow + 4 * lq + j) * 136 + n * 16 + lr] = (_Float16)v;
        }
    }

    if (HASX) {
        __syncthreads();
        stageB(B3t, Bs, tid);
        half8 hf[4];
        #pragma unroll
        for (int ks = 0; ks < 4; ++ks)
            hf[ks] = *(const half8*)&Ts[(trow + lr) * 136 + ks * 32 + lq * 8];
        __syncthreads();
        #pragma unroll
        for (int n = 0; n < 8; ++n) {
            f32x4 acc = {0.f, 0.f, 0.f, 0.f};
            #pragma unroll
            for (int ks = 0; ks < 4; ++ks) {
                half8 bf = *(const half8*)&Bs[bofs(n * 16 + lr, ks * 4 + lq)];
                acc = __builtin_amdgcn_mfma_f32_16x16x32_f16(hf[ks], bf, acc, 0, 0, 0);
            }
            #pragma unroll
            for (int j = 0; j < 4; ++j) {
                int row = r0 + 4 * lq + j;
                if (row < M) xout[(size_t)row * H + n * 16 + lr] = f2h(acc[j]);
            }
        }
    }
}

// ---------------- edge aggregation: 2 atoms/wave, 4 feats/lane, 8-deep ILP ----------------

__global__ __launch_bounds__(256) void edge_agg(const int* __restrict__ deg,
                                                const unsigned* __restrict__ meta,
                                                const unsigned short* __restrict__ x,
                                                const unsigned short* __restrict__ wt,
                                                unsigned short* __restrict__ agg) {
    int wv = threadIdx.x >> 6, ln = threadIdx.x & 63;
    int sub = ln >> 5, l32 = ln & 31;
    int i = (blockIdx.x << 3) + (wv << 1) + sub;
    if (i >= NA) return;
    int n = min(deg[i], PAD);
    const unsigned* mrow = meta + (size_t)i * PAD;
    int f4 = l32 << 2;
    float a0 = 0.f, a1 = 0.f, a2 = 0.f, a3 = 0.f;
    for (int p = 0; p < n; p += 8) {
        int rem = n - p;
        unsigned mm[8];
        #pragma unroll
        for (int j = 0; j < 8; ++j) mm[j] = mrow[p + min(j, rem - 1)];
        uint2 xv[8], wv8[8];
        #pragma unroll
        for (int j = 0; j < 8; ++j) {
            unsigned s = mm[j] & 0xFFFFu, idx = mm[j] >> 16;
            xv[j]  = *(const uint2*)(x  + (s   << 7) + f4);
            wv8[j] = *(const uint2*)(wt + (idx << 7) + f4);
        }
        #pragma unroll
        for (int j = 0; j < 8; ++j) {
            if (j < rem) {
                hpair xh0 = __builtin_bit_cast(hpair, xv[j].x);
                hpair wh0 = __builtin_bit_cast(hpair, wv8[j].x);
                hpair xh1 = __builtin_bit_cast(hpair, xv[j].y);
                hpair wh1 = __builtin_bit_cast(hpair, wv8[j].y);
                a0 += (float)xh0.x * (float)wh0.x;
                a1 += (float)xh0.y * (float)wh0.y;
                a2 += (float)xh1.x * (float)wh1.x;
                a3 += (float)xh1.y * (float)wh1.y;
            }
        }
    }
    hpair o0, o1;
    o0.x = (_Float16)a0; o0.y = (_Float16)a1;
    o1.x = (_Float16)a2; o1.y = (_Float16)a3;
    uint2 ov;
    ov.x = __builtin_bit_cast(unsigned, o0);
    ov.y = __builtin_bit_cast(unsigned, o1);
    *(uint2*)&agg[((size_t)i << 7) + f4] = ov;
}

// ---------------- readout ----------------

__global__ void mol_bounds(const int* __restrict__ a2c, const int* __restrict__ c2m,
                           int* __restrict__ ms, int* __restrict__ me) {
    int i = blockIdx.x * 256 + threadIdx.x;
    if (i >= NA) return;
    int m = c2m[a2c[i]];
    int mp = (i == 0) ? -1 : c2m[a2c[i - 1]];
    if (m != mp) ms[m] = i;
    int mn = (i == NA - 1) ? -1 : c2m[a2c[i + 1]];
    if (m != mn) me[m] = i + 1;
}

__global__ void mol_sum(const int* __restrict__ ms, const int* __restrict__ me,
                        const float* __restrict__ h2buf, float* __restrict__ mol) {
    int m = blockIdx.x, f = threadIdx.x;
    float acc = 0.f;
    int e0 = ms[m], e1 = me[m];
    for (int i = e0; i < e1; ++i) acc += h2buf[((size_t)i << 7) + f];
    mol[(m << 7) + f] = acc;
}

__global__ void final_mlp(const float* __restrict__ mol, const float* __restrict__ h1w,
                          const float* __restrict__ h1b, const float* __restrict__ h2w,
                          const float* __restrict__ h2b, float* __restrict__ out) {
    int m = blockIdx.x;
    int j = threadIdx.x;
    float acc = h1b[j];
    for (int k = 0; k < H; ++k) acc += mol[(m << 7) + k] * h1w[k * 64 + j];
    float hv = sspf(acc) * h2w[j];
    #pragma unroll
    for (int off = 32; off > 0; off >>= 1) hv += __shfl_down(hv, off);
    if (j == 0) out[m] = hv + h2b[0];
}

} // namespace

extern "C" void kernel_launch(void* const* d_in, const int* in_sizes, int n_in,
                              void* d_out, int out_size, void* d_ws, size_t ws_size,
                              hipStream_t stream) {
    const int*   z    = (const int*)d_in[0];
    const float* pos  = (const float*)d_in[1];
    const int*   ei   = (const int*)d_in[2];
    const int*   a2c  = (const int*)d_in[3];
    const int*   c2m  = (const int*)d_in[4];
    const float* emb  = (const float*)d_in[5];
    const float* iw1  = (const float*)d_in[6];
    const float* ib1  = (const float*)d_in[7];
    const float* iw2  = (const float*)d_in[8];
    const float* ib2  = (const float*)d_in[9];
    const float* il1  = (const float*)d_in[10];
    const float* il2w = (const float*)d_in[11];
    const float* il2b = (const float*)d_in[12];
    const float* ilw  = (const float*)d_in[13];
    const float* ilb  = (const float*)d_in[14];
    const float* l1w  = (const float*)d_in[15];
    const float* l1b  = (const float*)d_in[16];
    const float* l2w  = (const float*)d_in[17];
    const float* l2b  = (const float*)d_in[18];
    const float* h1w  = (const float*)d_in[19];
    const float* h1b  = (const float*)d_in[20];
    const float* h2w  = (const float*)d_in[21];
    const float* h2b  = (const float*)d_in[22];
    float* out = (float*)d_out;
    (void)in_sizes; (void)n_in; (void)out_size; (void)ws_size;

    char* base = (char*)d_ws;
    size_t off = 0;
    auto carve = [&](size_t bytes) -> char* {
        char* p = base + off;
        off += (bytes + 255) & ~(size_t)255;
        return p;
    };
    float*          h     = (float*)carve((size_t)NA * H * 4);
    unsigned short* xb    = (unsigned short*)carve((size_t)NA * H * 2);
    float*          agg   = (float*)carve((size_t)NA * H * 4);   // f16 during loop, f32 at end
    unsigned short* wtab  = (unsigned short*)carve((size_t)L * TBL * H * 2);
    unsigned*       meta  = (unsigned*)carve((size_t)NA * PAD * 4);
    int*            counts= (int*)carve((size_t)NA * 4);
    int*            ms    = (int*)carve((size_t)NM * 4);
    int*            me    = (int*)carve((size_t)NM * 4);
    float*          mol   = (float*)carve((size_t)NM * H * 4);
    unsigned short* il1t  = (unsigned short*)carve((size_t)L * H * H * 2);
    unsigned short* il2wt = (unsigned short*)carve((size_t)L * H * H * 2);
    unsigned short* ilwt  = (unsigned short*)carve((size_t)L * H * H * 2);
    unsigned short* l1wt  = (unsigned short*)carve((size_t)H * H * 2);
    unsigned short* l2wt  = (unsigned short*)carve((size_t)H * H * 2);
    unsigned short* iw1t  = (unsigned short*)carve((size_t)L * H * 64 * 2);
    unsigned short* iw2t  = (unsigned short*)carve((size_t)L * H * H * 2);
    unsigned short* aggh  = (unsigned short*)agg;

    hipMemsetAsync(counts, 0, (size_t)NA * 4, stream);
    edge_build<<<NE / 256, 256, 0, stream>>>(pos, ei, counts, meta);
    h_init<<<(NA * H) / 256, 256, 0, stream>>>(z, emb, h);

    convT<<<dim3(64, L), 256, 0, stream>>>(il1, il1t);
    convT<<<dim3(64, L), 256, 0, stream>>>(il2w, il2wt);
    convT<<<dim3(64, L), 256, 0, stream>>>(ilw, ilwt);
    convT<<<dim3(64, L), 256, 0, stream>>>(iw2, iw2t);
    convT<<<dim3(64, 1), 256, 0, stream>>>(l1w, l1wt);
    convT<<<dim3(64, 1), 256, 0, stream>>>(l2w, l2wt);
    convT_pad<<<dim3(32, L), 256, 0, stream>>>(iw1, iw1t);
    table_gemm<<<TBL / 64, 256, 0, stream>>>(iw1t, ib1, iw2t, ib2, wtab);

    const int NG = (NA + 63) / 64;   // 782
    gemm_xonly<<<NG, 256, 0, stream>>>(h, il1t /*unused slot*/ == nullptr ? nullptr : il1t, xb, NA);
    for (int k = 0; k < L; ++k) {
        edge_agg<<<(NA + 7) / 8, 256, 0, stream>>>(counts, meta, xb,
                                                   wtab + (size_t)k * TBL * H, aggh);
        if (k < L - 1) {
            node_fused<1, 1, 1><<<NG, 256, 0, stream>>>(aggh, nullptr,
                il2b + (size_t)k * H, il2wt + (size_t)k * H * H,
                h, h, ilb + (size_t)k * H, ilwt + (size_t)k * H * H,
                il1t + (size_t)(k + 1) * H * H, xb, NA);
        } else {
            node_fused<1, 0, 1><<<NG, 256, 0, stream>>>(aggh, nullptr,
                il2b + (size_t)k * H, il2wt + (size_t)k * H * H,
                h, h, ilb + (size_t)k * H, ilwt + (size_t)k * H * H,
                nullptr, nullptr, NA);
        }
    }
    // final: agg(f32) = ssp(h@l1w+l1b)@l2w+l2b
    node_fused<0, 0, 0><<<NG, 256, 0, stream>>>(nullptr, h, l1b, l1wt, nullptr, agg,
                                                l2b, l2wt, nullptr, nullptr, NA);

    hipMemsetAsync(ms, 0, (size_t)NM * 4, stream);
    hipMemsetAsync(me, 0, (size_t)NM * 4, stream);
    mol_bounds<<<(NA + 255) / 256, 256, 0, stream>>>(a2c, c2m, ms, me);
    mol_sum<<<NM, 128, 0, stream>>>(ms, me, agg, mol);
    final_mlp<<<NM, 64, 0, stream>>>(mol, h1w, h1b, h2w, h2b, out);
}

// Round 6
// 878.789 us; speedup vs baseline: 1.0858x; 1.0858x over previous
//
#include <hip/hip_runtime.h>
#include <math.h>

namespace {

constexpr int NA  = 50000;
constexpr int NE  = 1600000;
constexpr int NM  = 500;
constexpr int H   = 128;
constexpr int G   = 50;
constexpr int L   = 6;
constexpr int TBL = 8192;
constexpr int TSTR = (TBL + 1) * H;     // per-layer wtab stride (row TBL = zero row)
constexpr int PAD = 80;
constexpr float DMAX = 5.6f;

typedef _Float16 half8 __attribute__((ext_vector_type(8)));
typedef float f32x4 __attribute__((ext_vector_type(4)));
struct hpair { _Float16 x, y; };

__device__ __forceinline__ float sspf(float v) {
    return fmaxf(v, 0.0f) + log1pf(expf(-fabsf(v))) - 0.6931471805599453f;
}
__device__ __forceinline__ unsigned short f2h(float f) {
    _Float16 h = (_Float16)f;
    return __builtin_bit_cast(unsigned short, h);
}
__device__ __forceinline__ half8 cvt8(float4 a, float4 b) {
    half8 r;
    r[0] = (_Float16)a.x; r[1] = (_Float16)a.y; r[2] = (_Float16)a.z; r[3] = (_Float16)a.w;
    r[4] = (_Float16)b.x; r[5] = (_Float16)b.y; r[6] = (_Float16)b.z; r[7] = (_Float16)b.w;
    return r;
}
// B^T LDS granule offset with XOR swizzle for 128-u16 row pitch (G4)
__device__ __forceinline__ int bofs(int nrow, int g) {   // g = 16B granule 0..15
    int gs = (g & 8) | ((g ^ nrow) & 7);
    return nrow * 128 + gs * 8;
}
__device__ __forceinline__ void stageB(const unsigned short* __restrict__ Bt,
                                       unsigned short* Bs, int tid) {
    for (int i = tid; i < 2048; i += 256) {
        int row = i >> 4, g = i & 15;
        *(uint4*)&Bs[bofs(row, g)] = *(const uint4*)&Bt[i * 8];
    }
}

// ---------------- preprocessing: one-pass padded-CSR build ----------------

__global__ void edge_build(const float* __restrict__ pos, const int* __restrict__ ei,
                           int* __restrict__ counts, unsigned* __restrict__ meta) {
    int e = blockIdx.x * 256 + threadIdx.x;
    if (e >= NE) return;
    int s = ei[e], t = ei[NE + e];
    float dx = pos[3*s]   - pos[3*t];
    float dy = pos[3*s+1] - pos[3*t+1];
    float dz = pos[3*s+2] - pos[3*t+2];
    float d = sqrtf(dx*dx + dy*dy + dz*dz + 1e-12f);
    float u = d * ((float)(TBL - 1) / DMAX);
    if (u < (float)(TBL - 1)) {
        int idx = (int)(u + 0.5f);
        int r = atomicAdd(&counts[t], 1);
        if (r < PAD) meta[(size_t)t * PAD + r] = (unsigned)s | ((unsigned)idx << 16);
    }
}

// pad each row to a multiple of 8 with (s=0, idx=TBL) -> gathers the zero wtab row
__global__ void meta_pad(const int* __restrict__ deg, unsigned* __restrict__ meta) {
    int i = blockIdx.x * 256 + threadIdx.x;
    if (i >= NA) return;
    int n = min(deg[i], PAD);
    int n8 = (n + 7) & ~7;
    const unsigned pv = (unsigned)TBL << 16;
    for (int r = n; r < n8; ++r) meta[(size_t)i * PAD + r] = pv;
}

__global__ void h_init(const int* __restrict__ z, const float* __restrict__ emb,
                       float* __restrict__ h) {
    int idx = blockIdx.x * 256 + threadIdx.x;
    if (idx >= NA * H) return;
    int i = idx >> 7, f = idx & 127;
    h[idx] = emb[(z[i] << 7) + f];
}

// f32 [K=128][N=128] -> f16 B^T [N][K]
__global__ void convT(const float* __restrict__ src, unsigned short* __restrict__ dst) {
    int m = blockIdx.y;
    int e = blockIdx.x * 256 + threadIdx.x;   // e = n*128 + k
    int n = e >> 7, k = e & 127;
    dst[(size_t)m * 16384 + e] = f2h(src[(size_t)m * 16384 + k * 128 + n]);
}

// f32 [L][50][128] -> f16 B^T [L][128][64] (zero-padded K)
__global__ void convT_pad(const float* __restrict__ src, unsigned short* __restrict__ dst) {
    int l = blockIdx.y;
    int i = blockIdx.x * 256 + threadIdx.x;   // i = n*64 + k
    int n = i >> 6, k = i & 63;
    float v = (k < G) ? src[(size_t)l * G * H + k * H + n] : 0.0f;
    dst[(size_t)l * 8192 + i] = f2h(v);
}

// ---------------- filter tables via MFMA: grid (TBL/64, L) ----------------
// wtab[l][t][f] = (ssp(ea(d_t) @ iw1_l + b1) @ iw2_l + b2)[f] * C(d_t)

__global__ __launch_bounds__(256) void table_gemm(const unsigned short* __restrict__ iw1t,
                                                  const float* __restrict__ ib1,
                                                  const unsigned short* __restrict__ iw2t,
                                                  const float* __restrict__ ib2,
                                                  unsigned short* __restrict__ wtab) {
    __shared__ unsigned short Bs[16384];      // 32 KB
    __shared__ _Float16 Ts[64 * 136];         // 17 KB: ea staging, then t
    int l = blockIdx.y;
    int tid = threadIdx.x;
    int w = tid >> 6, lane = tid & 63, lr = lane & 15, lq = lane >> 4;
    int r0 = blockIdx.x * 64;
    int trow = w * 16;
    const float step  = DMAX / (float)(TBL - 1);
    const float sp    = 5.0f / 49.0f;
    const float coeff = -0.5f / (sp * sp);

    // stage iw1t_l [128 rows][64 u16] with 8-granule XOR swizzle -> Bs
    for (int i = tid; i < 1024; i += 256) {
        int row = i >> 3, g = i & 7;
        int gs = (g ^ row) & 7;
        *(uint4*)&Bs[row * 64 + gs * 8] = *(const uint4*)&iw1t[(size_t)l * 8192 + i * 8];
    }
    // stage ea (64 rows x 64 padded gaussians) -> Ts
    for (int i = tid; i < 64 * 64; i += 256) {
        int r = i >> 6, g = i & 63;
        float d = (float)(r0 + r) * step;
        float dd = d - (float)g * sp;
        Ts[r * 136 + g] = (_Float16)((g < G) ? expf(coeff * dd * dd) : 0.0f);
    }
    float Cj[4];
    #pragma unroll
    for (int j = 0; j < 4; ++j) {
        float d = (float)(r0 + trow + 4 * lq + j) * step;
        Cj[j] = 0.5f * (cosf(d * (3.14159265358979323846f / 5.0f)) + 1.0f);
    }
    __syncthreads();
    half8 af[2];
    #pragma unroll
    for (int ks = 0; ks < 2; ++ks)
        af[ks] = *(const half8*)&Ts[(trow + lr) * 136 + ks * 32 + lq * 8];
    __syncthreads();

    // pass A: t = ssp(ea @ iw1 + b1) -> Ts
    #pragma unroll
    for (int n = 0; n < 8; ++n) {
        f32x4 acc = {0.f, 0.f, 0.f, 0.f};
        #pragma unroll
        for (int ks = 0; ks < 2; ++ks) {
            int row = n * 16 + lr, g = ks * 4 + lq;
            half8 bf = *(const half8*)&Bs[row * 64 + ((g ^ row) & 7) * 8];
            acc = __builtin_amdgcn_mfma_f32_16x16x32_f16(af[ks], bf, acc, 0, 0, 0);
        }
        float b = ib1[l * H + n * 16 + lr];
        #pragma unroll
        for (int j = 0; j < 4; ++j)
            Ts[(trow + 4 * lq + j) * 136 + n * 16 + lr] = (_Float16)sspf(acc[j] + b);
    }
    __syncthreads();
    stageB(iw2t + (size_t)l * 16384, Bs, tid);
    half8 tf[4];
    #pragma unroll
    for (int ks = 0; ks < 4; ++ks)
        tf[ks] = *(const half8*)&Ts[(trow + lr) * 136 + ks * 32 + lq * 8];
    __syncthreads();
    // pass B: wtab = (t @ iw2 + b2) * C
    #pragma unroll
    for (int n = 0; n < 8; ++n) {
        f32x4 acc = {0.f, 0.f, 0.f, 0.f};
        #pragma unroll
        for (int ks = 0; ks < 4; ++ks) {
            half8 bf = *(const half8*)&Bs[bofs(n * 16 + lr, ks * 4 + lq)];
            acc = __builtin_amdgcn_mfma_f32_16x16x32_f16(tf[ks], bf, acc, 0, 0, 0);
        }
        float b = ib2[l * H + n * 16 + lr];
        #pragma unroll
        for (int j = 0; j < 4; ++j) {
            int row = r0 + trow + 4 * lq + j;
            wtab[(size_t)l * TSTR + (size_t)row * H + n * 16 + lr] =
                f2h((acc[j] + b) * Cj[j]);
        }
    }
}

// ---------------- standalone x = f16(h @ B)  (layer 0 only) ----------------

__global__ __launch_bounds__(256) void gemm_xonly(const float* __restrict__ A,
                                                  const unsigned short* __restrict__ Bt,
                                                  unsigned short* __restrict__ xout, int M) {
    __shared__ unsigned short Bs[16384];
    int tid = threadIdx.x;
    int w = tid >> 6, lane = tid & 63, lr = lane & 15, lq = lane >> 4;
    int r0 = blockIdx.x * 64 + w * 16;
    stageB(Bt, Bs, tid);
    const float* arow = A + (size_t)min(r0 + lr, M - 1) * H;
    half8 af[4];
    #pragma unroll
    for (int ks = 0; ks < 4; ++ks)
        af[ks] = cvt8(*(const float4*)(arow + ks * 32 + lq * 8),
                      *(const float4*)(arow + ks * 32 + lq * 8 + 4));
    __syncthreads();
    #pragma unroll
    for (int n = 0; n < 8; ++n) {
        f32x4 acc = {0.f, 0.f, 0.f, 0.f};
        #pragma unroll
        for (int ks = 0; ks < 4; ++ks) {
            half8 bf = *(const half8*)&Bs[bofs(n * 16 + lr, ks * 4 + lq)];
            acc = __builtin_amdgcn_mfma_f32_16x16x32_f16(af[ks], bf, acc, 0, 0, 0);
        }
        #pragma unroll
        for (int j = 0; j < 4; ++j) {
            int row = r0 + 4 * lq + j;
            if (row < M) xout[(size_t)row * H + n * 16 + lr] = f2h(acc[j]);
        }
    }
}

// ---------------- fused node update ----------------

template<int RES, int HASX, int AF16>
__global__ __launch_bounds__(256) void node_fused(const unsigned short* __restrict__ Ain16,
                                                  const float* __restrict__ Ain32,
                                                  const float* __restrict__ bias1,
                                                  const unsigned short* __restrict__ B1t,
                                                  const float* __restrict__ hres,
                                                  float* __restrict__ hout,
                                                  const float* __restrict__ bias2,
                                                  const unsigned short* __restrict__ B2t,
                                                  const unsigned short* __restrict__ B3t,
                                                  unsigned short* __restrict__ xout, int M) {
    __shared__ unsigned short Bs[16384];
    __shared__ _Float16 Ts[64 * 136];
    int tid = threadIdx.x;
    int w = tid >> 6, lane = tid & 63, lr = lane & 15, lq = lane >> 4;
    int r0 = blockIdx.x * 64 + w * 16;
    int trow = w * 16;

    stageB(B1t, Bs, tid);
    half8 af[4];
    if (AF16) {
        const unsigned short* arow = Ain16 + (size_t)min(r0 + lr, M - 1) * H;
        #pragma unroll
        for (int ks = 0; ks < 4; ++ks)
            af[ks] = *(const half8*)(arow + ks * 32 + lq * 8);
    } else {
        const float* arow = Ain32 + (size_t)min(r0 + lr, M - 1) * H;
        #pragma unroll
        for (int ks = 0; ks < 4; ++ks)
            af[ks] = cvt8(*(const float4*)(arow + ks * 32 + lq * 8),
                          *(const float4*)(arow + ks * 32 + lq * 8 + 4));
    }
    __syncthreads();

    #pragma unroll
    for (int n = 0; n < 8; ++n) {
        f32x4 acc = {0.f, 0.f, 0.f, 0.f};
        #pragma unroll
        for (int ks = 0; ks < 4; ++ks) {
            half8 bf = *(const half8*)&Bs[bofs(n * 16 + lr, ks * 4 + lq)];
            acc = __builtin_amdgcn_mfma_f32_16x16x32_f16(af[ks], bf, acc, 0, 0, 0);
        }
        float b = bias1[n * 16 + lr];
        #pragma unroll
        for (int j = 0; j < 4; ++j)
            Ts[(trow + 4 * lq + j) * 136 + n * 16 + lr] = (_Float16)sspf(acc[j] + b);
    }
    __syncthreads();
    stageB(B2t, Bs, tid);
    half8 tf[4];
    #pragma unroll
    for (int ks = 0; ks < 4; ++ks)
        tf[ks] = *(const half8*)&Ts[(trow + lr) * 136 + ks * 32 + lq * 8];
    __syncthreads();

    #pragma unroll
    for (int n = 0; n < 8; ++n) {
        f32x4 acc = {0.f, 0.f, 0.f, 0.f};
        #pragma unroll
        for (int ks = 0; ks < 4; ++ks) {
            half8 bf = *(const half8*)&Bs[bofs(n * 16 + lr, ks * 4 + lq)];
            acc = __builtin_amdgcn_mfma_f32_16x16x32_f16(tf[ks], bf, acc, 0, 0, 0);
        }
        float b = bias2[n * 16 + lr];
        #pragma unroll
        for (int j = 0; j < 4; ++j) {
            int row = r0 + 4 * lq + j;
            float v = acc[j] + b;
            if (RES) v += hres[(size_t)min(row, M - 1) * H + n * 16 + lr];
            if (row < M) hout[(size_t)row * H + n * 16 + lr] = v;
            if (HASX) Ts[(trow + 4 * lq + j) * 136 + n * 16 + lr] = (_Float16)v;
        }
    }

    if (HASX) {
        __syncthreads();
        stageB(B3t, Bs, tid);
        half8 hf[4];
        #pragma unroll
        for (int ks = 0; ks < 4; ++ks)
            hf[ks] = *(const half8*)&Ts[(trow + lr) * 136 + ks * 32 + lq * 8];
        __syncthreads();
        #pragma unroll
        for (int n = 0; n < 8; ++n) {
            f32x4 acc = {0.f, 0.f, 0.f, 0.f};
            #pragma unroll
            for (int ks = 0; ks < 4; ++ks) {
                half8 bf = *(const half8*)&Bs[bofs(n * 16 + lr, ks * 4 + lq)];
                acc = __builtin_amdgcn_mfma_f32_16x16x32_f16(hf[ks], bf, acc, 0, 0, 0);
            }
            #pragma unroll
            for (int j = 0; j < 4; ++j) {
                int row = r0 + 4 * lq + j;
                if (row < M) xout[(size_t)row * H + n * 16 + lr] = f2h(acc[j]);
            }
        }
    }
}

// ---------------- edge aggregation: 2 atoms/wave, 4 feats/lane, branch-free 8-deep ----------------

__global__ __launch_bounds__(256) void edge_agg(const int* __restrict__ deg,
                                                const unsigned* __restrict__ meta,
                                                const unsigned short* __restrict__ x,
                                                const unsigned short* __restrict__ wt,
                                                unsigned short* __restrict__ agg) {
    int wv = threadIdx.x >> 6, ln = threadIdx.x & 63;
    int sub = ln >> 5, l32 = ln & 31;
    int i = (blockIdx.x << 3) + (wv << 1) + sub;
    if (i >= NA) return;
    int n8 = (min(deg[i], PAD) + 7) & ~7;
    const unsigned* mrow = meta + (size_t)i * PAD;
    int f4 = l32 << 2;
    float a0 = 0.f, a1 = 0.f, a2 = 0.f, a3 = 0.f;
    for (int p = 0; p < n8; p += 8) {
        unsigned mm[8];
        #pragma unroll
        for (int j = 0; j < 8; ++j) mm[j] = mrow[p + j];
        uint2 xv[8], wv8[8];
        #pragma unroll
        for (int j = 0; j < 8; ++j) {
            unsigned s = mm[j] & 0xFFFFu, idx = mm[j] >> 16;
            xv[j]  = *(const uint2*)(x  + (s   << 7) + f4);
            wv8[j] = *(const uint2*)(wt + (idx << 7) + f4);
        }
        #pragma unroll
        for (int j = 0; j < 8; ++j) {
            hpair xh0 = __builtin_bit_cast(hpair, xv[j].x);
            hpair wh0 = __builtin_bit_cast(hpair, wv8[j].x);
            hpair xh1 = __builtin_bit_cast(hpair, xv[j].y);
            hpair wh1 = __builtin_bit_cast(hpair, wv8[j].y);
            a0 += (float)xh0.x * (float)wh0.x;
            a1 += (float)xh0.y * (float)wh0.y;
            a2 += (float)xh1.x * (float)wh1.x;
            a3 += (float)xh1.y * (float)wh1.y;
        }
    }
    hpair o0, o1;
    o0.x = (_Float16)a0; o0.y = (_Float16)a1;
    o1.x = (_Float16)a2; o1.y = (_Float16)a3;
    uint2 ov;
    ov.x = __builtin_bit_cast(unsigned, o0);
    ov.y = __builtin_bit_cast(unsigned, o1);
    *(uint2*)&agg[((size_t)i << 7) + f4] = ov;
}

// ---------------- readout ----------------

__global__ void mol_bounds(const int* __restrict__ a2c, const int* __restrict__ c2m,
                           int* __restrict__ ms, int* __restrict__ me) {
    int i = blockIdx.x * 256 + threadIdx.x;
    if (i >= NA) return;
    int m = c2m[a2c[i]];
    int mp = (i == 0) ? -1 : c2m[a2c[i - 1]];
    if (m != mp) ms[m] = i;
    int mn = (i == NA - 1) ? -1 : c2m[a2c[i + 1]];
    if (m != mn) me[m] = i + 1;
}

__global__ void mol_sum(const int* __restrict__ ms, const int* __restrict__ me,
                        const float* __restrict__ h2buf, float* __restrict__ mol) {
    int m = blockIdx.x, f = threadIdx.x;
    float acc = 0.f;
    int e0 = ms[m], e1 = me[m];
    for (int i = e0; i < e1; ++i) acc += h2buf[((size_t)i << 7) + f];
    mol[(m << 7) + f] = acc;
}

__global__ void final_mlp(const float* __restrict__ mol, const float* __restrict__ h1w,
                          const float* __restrict__ h1b, const float* __restrict__ h2w,
                          const float* __restrict__ h2b, float* __restrict__ out) {
    int m = blockIdx.x;
    int j = threadIdx.x;
    float acc = h1b[j];
    for (int k = 0; k < H; ++k) acc += mol[(m << 7) + k] * h1w[k * 64 + j];
    float hv = sspf(acc) * h2w[j];
    #pragma unroll
    for (int off = 32; off > 0; off >>= 1) hv += __shfl_down(hv, off);
    if (j == 0) out[m] = hv + h2b[0];
}

} // namespace

extern "C" void kernel_launch(void* const* d_in, const int* in_sizes, int n_in,
                              void* d_out, int out_size, void* d_ws, size_t ws_size,
                              hipStream_t stream) {
    const int*   z    = (const int*)d_in[0];
    const float* pos  = (const float*)d_in[1];
    const int*   ei   = (const int*)d_in[2];
    const int*   a2c  = (const int*)d_in[3];
    const int*   c2m  = (const int*)d_in[4];
    const float* emb  = (const float*)d_in[5];
    const float* iw1  = (const float*)d_in[6];
    const float* ib1  = (const float*)d_in[7];
    const float* iw2  = (const float*)d_in[8];
    const float* ib2  = (const float*)d_in[9];
    const float* il1  = (const float*)d_in[10];
    const float* il2w = (const float*)d_in[11];
    const float* il2b = (const float*)d_in[12];
    const float* ilw  = (const float*)d_in[13];
    const float* ilb  = (const float*)d_in[14];
    const float* l1w  = (const float*)d_in[15];
    const float* l1b  = (const float*)d_in[16];
    const float* l2w  = (const float*)d_in[17];
    const float* l2b  = (const float*)d_in[18];
    const float* h1w  = (const float*)d_in[19];
    const float* h1b  = (const float*)d_in[20];
    const float* h2w  = (const float*)d_in[21];
    const float* h2b  = (const float*)d_in[22];
    float* out = (float*)d_out;
    (void)in_sizes; (void)n_in; (void)out_size; (void)ws_size;

    char* base = (char*)d_ws;
    size_t off = 0;
    auto carve = [&](size_t bytes) -> char* {
        char* p = base + off;
        off += (bytes + 255) & ~(size_t)255;
        return p;
    };
    float*          h     = (float*)carve((size_t)NA * H * 4);
    unsigned short* xb    = (unsigned short*)carve((size_t)NA * H * 2);
    float*          agg   = (float*)carve((size_t)NA * H * 4);   // f16 during loop, f32 at end
    unsigned short* wtab  = (unsigned short*)carve((size_t)L * TSTR * 2);
    unsigned*       meta  = (unsigned*)carve((size_t)NA * PAD * 4);
    int*            counts= (int*)carve((size_t)NA * 4);
    int*            ms    = (int*)carve((size_t)NM * 4);
    int*            me    = (int*)carve((size_t)NM * 4);
    float*          mol   = (float*)carve((size_t)NM * H * 4);
    unsigned short* il1t  = (unsigned short*)carve((size_t)L * H * H * 2);
    unsigned short* il2wt = (unsigned short*)carve((size_t)L * H * H * 2);
    unsigned short* ilwt  = (unsigned short*)carve((size_t)L * H * H * 2);
    unsigned short* l1wt  = (unsigned short*)carve((size_t)H * H * 2);
    unsigned short* l2wt  = (unsigned short*)carve((size_t)H * H * 2);
    unsigned short* iw1t  = (unsigned short*)carve((size_t)L * H * 64 * 2);
    unsigned short* iw2t  = (unsigned short*)carve((size_t)L * H * H * 2);
    unsigned short* aggh  = (unsigned short*)agg;

    hipMemsetAsync(counts, 0, (size_t)NA * 4, stream);
    edge_build<<<NE / 256, 256, 0, stream>>>(pos, ei, counts, meta);
    meta_pad<<<(NA + 255) / 256, 256, 0, stream>>>(counts, meta);
    h_init<<<(NA * H) / 256, 256, 0, stream>>>(z, emb, h);

    convT<<<dim3(64, L), 256, 0, stream>>>(il1, il1t);
    convT<<<dim3(64, L), 256, 0, stream>>>(il2w, il2wt);
    convT<<<dim3(64, L), 256, 0, stream>>>(ilw, ilwt);
    convT<<<dim3(64, L), 256, 0, stream>>>(iw2, iw2t);
    convT<<<dim3(64, 1), 256, 0, stream>>>(l1w, l1wt);
    convT<<<dim3(64, 1), 256, 0, stream>>>(l2w, l2wt);
    convT_pad<<<dim3(32, L), 256, 0, stream>>>(iw1, iw1t);
    // zero row TBL of each layer's table (gathered by pad entries)
    for (int l = 0; l < L; ++l)
        hipMemsetAsync(wtab + (size_t)l * TSTR + (size_t)TBL * H, 0, H * 2, stream);
    table_gemm<<<dim3(TBL / 64, L), 256, 0, stream>>>(iw1t, ib1, iw2t, ib2, wtab);

    const int NG = (NA + 63) / 64;   // 782
    gemm_xonly<<<NG, 256, 0, stream>>>(h, il1t, xb, NA);
    for (int k = 0; k < L; ++k) {
        edge_agg<<<(NA + 7) / 8, 256, 0, stream>>>(counts, meta, xb,
                                                   wtab + (size_t)k * TSTR, aggh);
        if (k < L - 1) {
            node_fused<1, 1, 1><<<NG, 256, 0, stream>>>(aggh, nullptr,
                il2b + (size_t)k * H, il2wt + (size_t)k * H * H,
                h, h, ilb + (size_t)k * H, ilwt + (size_t)k * H * H,
                il1t + (size_t)(k + 1) * H * H, xb, NA);
        } else {
            node_fused<1, 0, 1><<<NG, 256, 0, stream>>>(aggh, nullptr,
                il2b + (size_t)k * H, il2wt + (size_t)k * H * H,
                h, h, ilb + (size_t)k * H, ilwt + (size_t)k * H * H,
                nullptr, nullptr, NA);
        }
    }
    // final: agg(f32) = ssp(h@l1w+l1b)@l2w+l2b
    node_fused<0, 0, 0><<<NG, 256, 0, stream>>>(nullptr, h, l1b, l1wt, nullptr, agg,
                                                l2b, l2wt, nullptr, nullptr, NA);

    hipMemsetAsync(ms, 0, (size_t)NM * 4, stream);
    hipMemsetAsync(me, 0, (size_t)NM * 4, stream);
    mol_bounds<<<(NA + 255) / 256, 256, 0, stream>>>(a2c, c2m, ms, me);
    mol_sum<<<NM, 128, 0, stream>>>(ms, me, agg, mol);
    final_mlp<<<NM, 64, 0, stream>>>(mol, h1w, h1b, h2w, h2b, out);
}

// Round 7
// 844.198 us; speedup vs baseline: 1.1303x; 1.0410x over previous
//
#include <hip/hip_runtime.h>
#include <math.h>

namespace {

constexpr int NA  = 50000;
constexpr int NE  = 1600000;
constexpr int NM  = 500;
constexpr int H   = 128;
constexpr int G   = 50;
constexpr int L   = 6;
constexpr int TBL = 8192;
constexpr int TSTR = (TBL + 1) * H;     // per-layer wtab stride (row TBL = zero row)
constexpr int PAD = 80;
constexpr float DMAX = 5.6f;

typedef _Float16 half8 __attribute__((ext_vector_type(8)));
typedef float f32x4 __attribute__((ext_vector_type(4)));
struct hpair { _Float16 x, y; };

__device__ __forceinline__ float sspf(float v) {
    return fmaxf(v, 0.0f) + log1pf(expf(-fabsf(v))) - 0.6931471805599453f;
}
__device__ __forceinline__ unsigned short f2h(float f) {
    _Float16 h = (_Float16)f;
    return __builtin_bit_cast(unsigned short, h);
}
__device__ __forceinline__ half8 cvt8(float4 a, float4 b) {
    half8 r;
    r[0] = (_Float16)a.x; r[1] = (_Float16)a.y; r[2] = (_Float16)a.z; r[3] = (_Float16)a.w;
    r[4] = (_Float16)b.x; r[5] = (_Float16)b.y; r[6] = (_Float16)b.z; r[7] = (_Float16)b.w;
    return r;
}
__device__ __forceinline__ float hlo(unsigned v) {
    return (float)__builtin_bit_cast(hpair, v).x;
}
__device__ __forceinline__ float hhi(unsigned v) {
    return (float)__builtin_bit_cast(hpair, v).y;
}
// B^T LDS granule offset with XOR swizzle for 128-u16 row pitch (G4)
__device__ __forceinline__ int bofs(int nrow, int g) {   // g = 16B granule 0..15
    int gs = (g & 8) | ((g ^ nrow) & 7);
    return nrow * 128 + gs * 8;
}
__device__ __forceinline__ void stageB(const unsigned short* __restrict__ Bt,
                                       unsigned short* Bs, int tid) {
    for (int i = tid; i < 2048; i += 256) {
        int row = i >> 4, g = i & 15;
        *(uint4*)&Bs[bofs(row, g)] = *(const uint4*)&Bt[i * 8];
    }
}

// ---------------- preprocessing: one-pass padded-CSR build ----------------

__global__ void edge_build(const float* __restrict__ pos, const int* __restrict__ ei,
                           int* __restrict__ counts, unsigned* __restrict__ meta) {
    int e = blockIdx.x * 256 + threadIdx.x;
    if (e >= NE) return;
    int s = ei[e], t = ei[NE + e];
    float dx = pos[3*s]   - pos[3*t];
    float dy = pos[3*s+1] - pos[3*t+1];
    float dz = pos[3*s+2] - pos[3*t+2];
    float d = sqrtf(dx*dx + dy*dy + dz*dz + 1e-12f);
    float u = d * ((float)(TBL - 1) / DMAX);
    if (u < (float)(TBL - 1)) {
        int idx = (int)(u + 0.5f);
        int r = atomicAdd(&counts[t], 1);
        if (r < PAD) meta[(size_t)t * PAD + r] = (unsigned)s | ((unsigned)idx << 16);
    }
}

// pad each row to a multiple of 8 with (s=0, idx=TBL) -> gathers the zero wtab row
__global__ void meta_pad(const int* __restrict__ deg, unsigned* __restrict__ meta) {
    int i = blockIdx.x * 256 + threadIdx.x;
    if (i >= NA) return;
    int n = min(deg[i], PAD);
    int n8 = (n + 7) & ~7;
    const unsigned pv = (unsigned)TBL << 16;
    for (int r = n; r < n8; ++r) meta[(size_t)i * PAD + r] = pv;
}

// f32 [K=128][N=128] -> f16 B^T [N][K]
__global__ void convT(const float* __restrict__ src, unsigned short* __restrict__ dst) {
    int m = blockIdx.y;
    int e = blockIdx.x * 256 + threadIdx.x;   // e = n*128 + k
    int n = e >> 7, k = e & 127;
    dst[(size_t)m * 16384 + e] = f2h(src[(size_t)m * 16384 + k * 128 + n]);
}

// f32 [L][50][128] -> f16 B^T [L][128][64] (zero-padded K)
__global__ void convT_pad(const float* __restrict__ src, unsigned short* __restrict__ dst) {
    int l = blockIdx.y;
    int i = blockIdx.x * 256 + threadIdx.x;   // i = n*64 + k
    int n = i >> 6, k = i & 63;
    float v = (k < G) ? src[(size_t)l * G * H + k * H + n] : 0.0f;
    dst[(size_t)l * 8192 + i] = f2h(v);
}

// ---------------- filter tables via MFMA: grid (TBL/64, L) ----------------

__global__ __launch_bounds__(256) void table_gemm(const unsigned short* __restrict__ iw1t,
                                                  const float* __restrict__ ib1,
                                                  const unsigned short* __restrict__ iw2t,
                                                  const float* __restrict__ ib2,
                                                  unsigned short* __restrict__ wtab) {
    __shared__ unsigned short Bs[16384];      // 32 KB
    __shared__ _Float16 Ts[64 * 136];         // 17 KB: ea staging, then t
    int l = blockIdx.y;
    int tid = threadIdx.x;
    int w = tid >> 6, lane = tid & 63, lr = lane & 15, lq = lane >> 4;
    int r0 = blockIdx.x * 64;
    int trow = w * 16;
    const float step  = DMAX / (float)(TBL - 1);
    const float sp    = 5.0f / 49.0f;
    const float coeff = -0.5f / (sp * sp);

    // layer's zero row (gathered by pad entries)
    if (blockIdx.x == 0 && tid < H)
        wtab[(size_t)l * TSTR + (size_t)TBL * H + tid] = 0;

    for (int i = tid; i < 1024; i += 256) {
        int row = i >> 3, g = i & 7;
        int gs = (g ^ row) & 7;
        *(uint4*)&Bs[row * 64 + gs * 8] = *(const uint4*)&iw1t[(size_t)l * 8192 + i * 8];
    }
    for (int i = tid; i < 64 * 64; i += 256) {
        int r = i >> 6, g = i & 63;
        float d = (float)(r0 + r) * step;
        float dd = d - (float)g * sp;
        Ts[r * 136 + g] = (_Float16)((g < G) ? expf(coeff * dd * dd) : 0.0f);
    }
    float Cj[4];
    #pragma unroll
    for (int j = 0; j < 4; ++j) {
        float d = (float)(r0 + trow + 4 * lq + j) * step;
        Cj[j] = 0.5f * (cosf(d * (3.14159265358979323846f / 5.0f)) + 1.0f);
    }
    __syncthreads();
    half8 af[2];
    #pragma unroll
    for (int ks = 0; ks < 2; ++ks)
        af[ks] = *(const half8*)&Ts[(trow + lr) * 136 + ks * 32 + lq * 8];
    __syncthreads();

    #pragma unroll
    for (int n = 0; n < 8; ++n) {
        f32x4 acc = {0.f, 0.f, 0.f, 0.f};
        #pragma unroll
        for (int ks = 0; ks < 2; ++ks) {
            int row = n * 16 + lr, g = ks * 4 + lq;
            half8 bf = *(const half8*)&Bs[row * 64 + ((g ^ row) & 7) * 8];
            acc = __builtin_amdgcn_mfma_f32_16x16x32_f16(af[ks], bf, acc, 0, 0, 0);
        }
        float b = ib1[l * H + n * 16 + lr];
        #pragma unroll
        for (int j = 0; j < 4; ++j)
            Ts[(trow + 4 * lq + j) * 136 + n * 16 + lr] = (_Float16)sspf(acc[j] + b);
    }
    __syncthreads();
    stageB(iw2t + (size_t)l * 16384, Bs, tid);
    half8 tf[4];
    #pragma unroll
    for (int ks = 0; ks < 4; ++ks)
        tf[ks] = *(const half8*)&Ts[(trow + lr) * 136 + ks * 32 + lq * 8];
    __syncthreads();
    #pragma unroll
    for (int n = 0; n < 8; ++n) {
        f32x4 acc = {0.f, 0.f, 0.f, 0.f};
        #pragma unroll
        for (int ks = 0; ks < 4; ++ks) {
            half8 bf = *(const half8*)&Bs[bofs(n * 16 + lr, ks * 4 + lq)];
            acc = __builtin_amdgcn_mfma_f32_16x16x32_f16(tf[ks], bf, acc, 0, 0, 0);
        }
        float b = ib2[l * H + n * 16 + lr];
        #pragma unroll
        for (int j = 0; j < 4; ++j) {
            int row = r0 + trow + 4 * lq + j;
            wtab[(size_t)l * TSTR + (size_t)row * H + n * 16 + lr] =
                f2h((acc[j] + b) * Cj[j]);
        }
    }
}

// ---------------- fused h-init + x = f16(emb[z] @ B)  (layer 0) ----------------

__global__ __launch_bounds__(256) void gemm_hx(const int* __restrict__ z,
                                               const float* __restrict__ emb,
                                               const unsigned short* __restrict__ Bt,
                                               float* __restrict__ hout,
                                               unsigned short* __restrict__ xout, int M) {
    __shared__ unsigned short Bs[16384];
    int tid = threadIdx.x;
    int w = tid >> 6, lane = tid & 63, lr = lane & 15, lq = lane >> 4;
    int r0 = blockIdx.x * 64 + w * 16;
    stageB(Bt, Bs, tid);
    int row = min(r0 + lr, M - 1);
    const float* arow = emb + (size_t)z[row] * H;
    half8 af[4];
    #pragma unroll
    for (int ks = 0; ks < 4; ++ks) {
        float4 a = *(const float4*)(arow + ks * 32 + lq * 8);
        float4 b = *(const float4*)(arow + ks * 32 + lq * 8 + 4);
        af[ks] = cvt8(a, b);
        if (r0 + lr < M) {
            *(float4*)&hout[(size_t)(r0 + lr) * H + ks * 32 + lq * 8] = a;
            *(float4*)&hout[(size_t)(r0 + lr) * H + ks * 32 + lq * 8 + 4] = b;
        }
    }
    __syncthreads();
    #pragma unroll
    for (int n = 0; n < 8; ++n) {
        f32x4 acc = {0.f, 0.f, 0.f, 0.f};
        #pragma unroll
        for (int ks = 0; ks < 4; ++ks) {
            half8 bf = *(const half8*)&Bs[bofs(n * 16 + lr, ks * 4 + lq)];
            acc = __builtin_amdgcn_mfma_f32_16x16x32_f16(af[ks], bf, acc, 0, 0, 0);
        }
        #pragma unroll
        for (int j = 0; j < 4; ++j) {
            int orow = r0 + 4 * lq + j;
            if (orow < M) xout[(size_t)orow * H + n * 16 + lr] = f2h(acc[j]);
        }
    }
}

// ---------------- fused node update ----------------

template<int RES, int HASX, int AF16>
__global__ __launch_bounds__(256) void node_fused(const unsigned short* __restrict__ Ain16,
                                                  const float* __restrict__ Ain32,
                                                  const float* __restrict__ bias1,
                                                  const unsigned short* __restrict__ B1t,
                                                  const float* __restrict__ hres,
                                                  float* __restrict__ hout,
                                                  const float* __restrict__ bias2,
                                                  const unsigned short* __restrict__ B2t,
                                                  const unsigned short* __restrict__ B3t,
                                                  unsigned short* __restrict__ xout, int M) {
    __shared__ unsigned short Bs[16384];
    __shared__ _Float16 Ts[64 * 136];
    int tid = threadIdx.x;
    int w = tid >> 6, lane = tid & 63, lr = lane & 15, lq = lane >> 4;
    int r0 = blockIdx.x * 64 + w * 16;
    int trow = w * 16;

    stageB(B1t, Bs, tid);
    half8 af[4];
    if (AF16) {
        const unsigned short* arow = Ain16 + (size_t)min(r0 + lr, M - 1) * H;
        #pragma unroll
        for (int ks = 0; ks < 4; ++ks)
            af[ks] = *(const half8*)(arow + ks * 32 + lq * 8);
    } else {
        const float* arow = Ain32 + (size_t)min(r0 + lr, M - 1) * H;
        #pragma unroll
        for (int ks = 0; ks < 4; ++ks)
            af[ks] = cvt8(*(const float4*)(arow + ks * 32 + lq * 8),
                          *(const float4*)(arow + ks * 32 + lq * 8 + 4));
    }
    __syncthreads();

    #pragma unroll
    for (int n = 0; n < 8; ++n) {
        f32x4 acc = {0.f, 0.f, 0.f, 0.f};
        #pragma unroll
        for (int ks = 0; ks < 4; ++ks) {
            half8 bf = *(const half8*)&Bs[bofs(n * 16 + lr, ks * 4 + lq)];
            acc = __builtin_amdgcn_mfma_f32_16x16x32_f16(af[ks], bf, acc, 0, 0, 0);
        }
        float b = bias1[n * 16 + lr];
        #pragma unroll
        for (int j = 0; j < 4; ++j)
            Ts[(trow + 4 * lq + j) * 136 + n * 16 + lr] = (_Float16)sspf(acc[j] + b);
    }
    __syncthreads();
    stageB(B2t, Bs, tid);
    half8 tf[4];
    #pragma unroll
    for (int ks = 0; ks < 4; ++ks)
        tf[ks] = *(const half8*)&Ts[(trow + lr) * 136 + ks * 32 + lq * 8];
    __syncthreads();

    #pragma unroll
    for (int n = 0; n < 8; ++n) {
        f32x4 acc = {0.f, 0.f, 0.f, 0.f};
        #pragma unroll
        for (int ks = 0; ks < 4; ++ks) {
            half8 bf = *(const half8*)&Bs[bofs(n * 16 + lr, ks * 4 + lq)];
            acc = __builtin_amdgcn_mfma_f32_16x16x32_f16(tf[ks], bf, acc, 0, 0, 0);
        }
        float b = bias2[n * 16 + lr];
        #pragma unroll
        for (int j = 0; j < 4; ++j) {
            int row = r0 + 4 * lq + j;
            float v = acc[j] + b;
            if (RES) v += hres[(size_t)min(row, M - 1) * H + n * 16 + lr];
            if (row < M) hout[(size_t)row * H + n * 16 + lr] = v;
            if (HASX) Ts[(trow + 4 * lq + j) * 136 + n * 16 + lr] = (_Float16)v;
        }
    }

    if (HASX) {
        __syncthreads();
        stageB(B3t, Bs, tid);
        half8 hf[4];
        #pragma unroll
        for (int ks = 0; ks < 4; ++ks)
            hf[ks] = *(const half8*)&Ts[(trow + lr) * 136 + ks * 32 + lq * 8];
        __syncthreads();
        #pragma unroll
        for (int n = 0; n < 8; ++n) {
            f32x4 acc = {0.f, 0.f, 0.f, 0.f};
            #pragma unroll
            for (int ks = 0; ks < 4; ++ks) {
                half8 bf = *(const half8*)&Bs[bofs(n * 16 + lr, ks * 4 + lq)];
                acc = __builtin_amdgcn_mfma_f32_16x16x32_f16(hf[ks], bf, acc, 0, 0, 0);
            }
            #pragma unroll
            for (int j = 0; j < 4; ++j) {
                int row = r0 + 4 * lq + j;
                if (row < M) xout[(size_t)row * H + n * 16 + lr] = f2h(acc[j]);
            }
        }
    }
}

// ---------------- edge aggregation: 4 atoms/wave, 16 lanes x 8 feats, uint4 gathers ----------------

__global__ __launch_bounds__(256) void edge_agg(const int* __restrict__ deg,
                                                const unsigned* __restrict__ meta,
                                                const unsigned short* __restrict__ x,
                                                const unsigned short* __restrict__ wt,
                                                unsigned short* __restrict__ agg) {
    int wv = threadIdx.x >> 6, ln = threadIdx.x & 63;
    int a = ln >> 4, fl = ln & 15;
    int i = (blockIdx.x << 4) + (wv << 2) + a;   // grid covers NA exactly
    int n8 = (min(deg[i], PAD) + 7) & ~7;
    const unsigned* mrow = meta + (size_t)i * PAD;
    int f8 = fl << 3;
    float acc[8] = {};
    for (int p = 0; p < n8; p += 8) {
        unsigned mm[8];
        #pragma unroll
        for (int j = 0; j < 8; ++j) mm[j] = mrow[p + j];
        uint4 xv[8], wv8[8];
        #pragma unroll
        for (int j = 0; j < 8; ++j) {
            unsigned s = mm[j] & 0xFFFFu, idx = mm[j] >> 16;
            xv[j]  = *(const uint4*)(x  + ((size_t)s   << 7) + f8);
            wv8[j] = *(const uint4*)(wt + ((size_t)idx << 7) + f8);
        }
        #pragma unroll
        for (int j = 0; j < 8; ++j) {
            acc[0] += hlo(xv[j].x) * hlo(wv8[j].x);
            acc[1] += hhi(xv[j].x) * hhi(wv8[j].x);
            acc[2] += hlo(xv[j].y) * hlo(wv8[j].y);
            acc[3] += hhi(xv[j].y) * hhi(wv8[j].y);
            acc[4] += hlo(xv[j].z) * hlo(wv8[j].z);
            acc[5] += hhi(xv[j].z) * hhi(wv8[j].z);
            acc[6] += hlo(xv[j].w) * hlo(wv8[j].w);
            acc[7] += hhi(xv[j].w) * hhi(wv8[j].w);
        }
    }
    uint4 ov;
    ov.x = (unsigned)f2h(acc[0]) | ((unsigned)f2h(acc[1]) << 16);
    ov.y = (unsigned)f2h(acc[2]) | ((unsigned)f2h(acc[3]) << 16);
    ov.z = (unsigned)f2h(acc[4]) | ((unsigned)f2h(acc[5]) << 16);
    ov.w = (unsigned)f2h(acc[6]) | ((unsigned)f2h(acc[7]) << 16);
    *(uint4*)&agg[((size_t)i << 7) + f8] = ov;
}

// ---------------- readout ----------------

__global__ void mol_bounds(const int* __restrict__ a2c, const int* __restrict__ c2m,
                           int* __restrict__ ms, int* __restrict__ me) {
    int i = blockIdx.x * 256 + threadIdx.x;
    if (i >= NA) return;
    int m = c2m[a2c[i]];
    int mp = (i == 0) ? -1 : c2m[a2c[i - 1]];
    if (m != mp) ms[m] = i;
    int mn = (i == NA - 1) ? -1 : c2m[a2c[i + 1]];
    if (m != mn) me[m] = i + 1;
}

__global__ __launch_bounds__(512) void mol_sum(const int* __restrict__ ms, const int* __restrict__ me,
                                               const float* __restrict__ h2buf, float* __restrict__ mol) {
    __shared__ float red[4][128];
    int m = blockIdx.x;
    int f = threadIdx.x & 127, q = threadIdx.x >> 7;
    float acc = 0.f;
    int e0 = ms[m], e1 = me[m];
    for (int i = e0 + q; i < e1; i += 4) acc += h2buf[((size_t)i << 7) + f];
    red[q][f] = acc;
    __syncthreads();
    if (q == 0) mol[(m << 7) + f] = red[0][f] + red[1][f] + red[2][f] + red[3][f];
}

__global__ void final_mlp(const float* __restrict__ mol, const float* __restrict__ h1w,
                          const float* __restrict__ h1b, const float* __restrict__ h2w,
                          const float* __restrict__ h2b, float* __restrict__ out) {
    int m = blockIdx.x;
    int j = threadIdx.x;
    float acc = h1b[j];
    for (int k = 0; k < H; ++k) acc += mol[(m << 7) + k] * h1w[k * 64 + j];
    float hv = sspf(acc) * h2w[j];
    #pragma unroll
    for (int off = 32; off > 0; off >>= 1) hv += __shfl_down(hv, off);
    if (j == 0) out[m] = hv + h2b[0];
}

} // namespace

extern "C" void kernel_launch(void* const* d_in, const int* in_sizes, int n_in,
                              void* d_out, int out_size, void* d_ws, size_t ws_size,
                              hipStream_t stream) {
    const int*   z    = (const int*)d_in[0];
    const float* pos  = (const float*)d_in[1];
    const int*   ei   = (const int*)d_in[2];
    const int*   a2c  = (const int*)d_in[3];
    const int*   c2m  = (const int*)d_in[4];
    const float* emb  = (const float*)d_in[5];
    const float* iw1  = (const float*)d_in[6];
    const float* ib1  = (const float*)d_in[7];
    const float* iw2  = (const float*)d_in[8];
    const float* ib2  = (const float*)d_in[9];
    const float* il1  = (const float*)d_in[10];
    const float* il2w = (const float*)d_in[11];
    const float* il2b = (const float*)d_in[12];
    const float* ilw  = (const float*)d_in[13];
    const float* ilb  = (const float*)d_in[14];
    const float* l1w  = (const float*)d_in[15];
    const float* l1b  = (const float*)d_in[16];
    const float* l2w  = (const float*)d_in[17];
    const float* l2b  = (const float*)d_in[18];
    const float* h1w  = (const float*)d_in[19];
    const float* h1b  = (const float*)d_in[20];
    const float* h2w  = (const float*)d_in[21];
    const float* h2b  = (const float*)d_in[22];
    float* out = (float*)d_out;
    (void)in_sizes; (void)n_in; (void)out_size; (void)ws_size;

    char* base = (char*)d_ws;
    size_t off = 0;
    auto carve = [&](size_t bytes) -> char* {
        char* p = base + off;
        off += (bytes + 255) & ~(size_t)255;
        return p;
    };
    float*          h     = (float*)carve((size_t)NA * H * 4);
    unsigned short* xb    = (unsigned short*)carve((size_t)NA * H * 2);
    float*          agg   = (float*)carve((size_t)NA * H * 4);   // f16 during loop, f32 at end
    unsigned short* wtab  = (unsigned short*)carve((size_t)L * TSTR * 2);
    unsigned*       meta  = (unsigned*)carve((size_t)NA * PAD * 4);
    int*            counts= (int*)carve((size_t)NA * 4);
    int*            ms    = (int*)carve((size_t)NM * 4);
    int*            me    = (int*)carve((size_t)NM * 4);
    float*          mol   = (float*)carve((size_t)NM * H * 4);
    unsigned short* il1t  = (unsigned short*)carve((size_t)L * H * H * 2);
    unsigned short* il2wt = (unsigned short*)carve((size_t)L * H * H * 2);
    unsigned short* ilwt  = (unsigned short*)carve((size_t)L * H * H * 2);
    unsigned short* l1wt  = (unsigned short*)carve((size_t)H * H * 2);
    unsigned short* l2wt  = (unsigned short*)carve((size_t)H * H * 2);
    unsigned short* iw1t  = (unsigned short*)carve((size_t)L * H * 64 * 2);
    unsigned short* iw2t  = (unsigned short*)carve((size_t)L * H * H * 2);
    unsigned short* aggh  = (unsigned short*)agg;

    hipMemsetAsync(counts, 0, (size_t)NA * 4, stream);
    edge_build<<<NE / 256, 256, 0, stream>>>(pos, ei, counts, meta);
    meta_pad<<<(NA + 255) / 256, 256, 0, stream>>>(counts, meta);

    convT<<<dim3(64, L), 256, 0, stream>>>(il1, il1t);
    convT<<<dim3(64, L), 256, 0, stream>>>(il2w, il2wt);
    convT<<<dim3(64, L), 256, 0, stream>>>(ilw, ilwt);
    convT<<<dim3(64, L), 256, 0, stream>>>(iw2, iw2t);
    convT<<<dim3(64, 1), 256, 0, stream>>>(l1w, l1wt);
    convT<<<dim3(64, 1), 256, 0, stream>>>(l2w, l2wt);
    convT_pad<<<dim3(32, L), 256, 0, stream>>>(iw1, iw1t);
    table_gemm<<<dim3(TBL / 64, L), 256, 0, stream>>>(iw1t, ib1, iw2t, ib2, wtab);

    const int NG = (NA + 63) / 64;   // 782
    gemm_hx<<<NG, 256, 0, stream>>>(z, emb, il1t, h, xb, NA);
    for (int k = 0; k < L; ++k) {
        edge_agg<<<NA / 16, 256, 0, stream>>>(counts, meta, xb,
                                              wtab + (size_t)k * TSTR, aggh);
        if (k < L - 1) {
            node_fused<1, 1, 1><<<NG, 256, 0, stream>>>(aggh, nullptr,
                il2b + (size_t)k * H, il2wt + (size_t)k * H * H,
                h, h, ilb + (size_t)k * H, ilwt + (size_t)k * H * H,
                il1t + (size_t)(k + 1) * H * H, xb, NA);
        } else {
            node_fused<1, 0, 1><<<NG, 256, 0, stream>>>(aggh, nullptr,
                il2b + (size_t)k * H, il2wt + (size_t)k * H * H,
                h, h, ilb + (size_t)k * H, ilwt + (size_t)k * H * H,
                nullptr, nullptr, NA);
        }
    }
    // final: agg(f32) = ssp(h@l1w+l1b)@l2w+l2b
    node_fused<0, 0, 0><<<NG, 256, 0, stream>>>(nullptr, h, l1b, l1wt, nullptr, agg,
                                                l2b, l2wt, nullptr, nullptr, NA);

    hipMemsetAsync(ms, 0, (size_t)NM * 4, stream);
    hipMemsetAsync(me, 0, (size_t)NM * 4, stream);
    mol_bounds<<<(NA + 255) / 256, 256, 0, stream>>>(a2c, c2m, ms, me);
    mol_sum<<<NM, 512, 0, stream>>>(ms, me, agg, mol);
    final_mlp<<<NM, 64, 0, stream>>>(mol, h1w, h1b, h2w, h2b, out);
}

// Round 8
// 824.401 us; speedup vs baseline: 1.1575x; 1.0240x over previous
//
#include <hip/hip_runtime.h>
#include <math.h>

namespace {

constexpr int NA  = 50000;
constexpr int NE  = 1600000;
constexpr int NM  = 500;
constexpr int H   = 128;
constexpr int G   = 50;
constexpr int L   = 6;
constexpr int TBL = 8192;
constexpr int TSTR = (TBL + 1) * H;     // per-layer wtab stride (row TBL = zero row)
constexpr int PAD = 80;
constexpr float DMAX = 5.6f;

typedef _Float16 half8 __attribute__((ext_vector_type(8)));
typedef float f32x4 __attribute__((ext_vector_type(4)));
struct hpair { _Float16 x, y; };

__device__ __forceinline__ float sspf(float v) {
    return fmaxf(v, 0.0f) + log1pf(expf(-fabsf(v))) - 0.6931471805599453f;
}
__device__ __forceinline__ unsigned short f2h(float f) {
    _Float16 h = (_Float16)f;
    return __builtin_bit_cast(unsigned short, h);
}
__device__ __forceinline__ half8 cvt8(float4 a, float4 b) {
    half8 r;
    r[0] = (_Float16)a.x; r[1] = (_Float16)a.y; r[2] = (_Float16)a.z; r[3] = (_Float16)a.w;
    r[4] = (_Float16)b.x; r[5] = (_Float16)b.y; r[6] = (_Float16)b.z; r[7] = (_Float16)b.w;
    return r;
}
__device__ __forceinline__ float hlo(unsigned v) {
    return (float)__builtin_bit_cast(hpair, v).x;
}
__device__ __forceinline__ float hhi(unsigned v) {
    return (float)__builtin_bit_cast(hpair, v).y;
}
// B^T LDS granule offset with XOR swizzle for 128-u16 row pitch (G4)
__device__ __forceinline__ int bofs(int nrow, int g) {   // g = 16B granule 0..15
    int gs = (g & 8) | ((g ^ nrow) & 7);
    return nrow * 128 + gs * 8;
}
__device__ __forceinline__ void stageB(const unsigned short* __restrict__ Bt,
                                       unsigned short* Bs, int tid) {
    for (int i = tid; i < 2048; i += 256) {
        int row = i >> 4, g = i & 15;
        *(uint4*)&Bs[bofs(row, g)] = *(const uint4*)&Bt[i * 8];
    }
}

// ---------------- preprocessing: one-pass padded-CSR build ----------------

__global__ void edge_build(const float* __restrict__ pos, const int* __restrict__ ei,
                           int* __restrict__ counts, unsigned* __restrict__ meta) {
    int e = blockIdx.x * 256 + threadIdx.x;
    if (e >= NE) return;
    int s = ei[e], t = ei[NE + e];
    float dx = pos[3*s]   - pos[3*t];
    float dy = pos[3*s+1] - pos[3*t+1];
    float dz = pos[3*s+2] - pos[3*t+2];
    float d = sqrtf(dx*dx + dy*dy + dz*dz + 1e-12f);
    float u = d * ((float)(TBL - 1) / DMAX);
    if (u < (float)(TBL - 1)) {
        int idx = (int)(u + 0.5f);
        int r = atomicAdd(&counts[t], 1);
        if (r < PAD) meta[(size_t)t * PAD + r] = (unsigned)s | ((unsigned)idx << 16);
    }
}

// pad each row to a multiple of 8 with (s=0, idx=TBL) -> gathers the zero wtab row
__global__ void meta_pad(const int* __restrict__ deg, unsigned* __restrict__ meta) {
    int i = blockIdx.x * 256 + threadIdx.x;
    if (i >= NA) return;
    int n = min(deg[i], PAD);
    int n8 = (n + 7) & ~7;
    const unsigned pv = (unsigned)TBL << 16;
    for (int r = n; r < n8; ++r) meta[(size_t)i * PAD + r] = pv;
}

// ---------------- one-launch weight prep: f32 [K][N] -> f16 B^T [N][K] (+ padded iw1) ----------------

__global__ void prep_weights(const float* __restrict__ il1, const float* __restrict__ il2w,
                             const float* __restrict__ ilw, const float* __restrict__ iw2,
                             const float* __restrict__ l1w, const float* __restrict__ l2w,
                             const float* __restrict__ iw1,
                             unsigned short* __restrict__ il1t, unsigned short* __restrict__ il2wt,
                             unsigned short* __restrict__ ilwt, unsigned short* __restrict__ iw2t,
                             unsigned short* __restrict__ l1wt, unsigned short* __restrict__ l2wt,
                             unsigned short* __restrict__ iw1t) {
    int m = blockIdx.y;
    int e = blockIdx.x * 256 + threadIdx.x;
    if (m < 26) {
        const float* src; unsigned short* dst;
        if (m < 6)       { src = il1  + (size_t)m * 16384;        dst = il1t  + (size_t)m * 16384; }
        else if (m < 12) { src = il2w + (size_t)(m - 6) * 16384;  dst = il2wt + (size_t)(m - 6) * 16384; }
        else if (m < 18) { src = ilw  + (size_t)(m - 12) * 16384; dst = ilwt  + (size_t)(m - 12) * 16384; }
        else if (m < 24) { src = iw2  + (size_t)(m - 18) * 16384; dst = iw2t  + (size_t)(m - 18) * 16384; }
        else if (m == 24){ src = l1w; dst = l1wt; }
        else             { src = l2w; dst = l2wt; }
        int n = e >> 7, k = e & 127;
        dst[e] = f2h(src[k * 128 + n]);
    } else {
        int l = m - 26;
        if (e < 8192) {
            int n = e >> 6, k = e & 63;
            float v = (k < G) ? iw1[(size_t)l * G * H + k * H + n] : 0.0f;
            iw1t[(size_t)l * 8192 + e] = f2h(v);
        }
    }
}

// ---------------- filter tables via MFMA: grid (TBL/64, L) ----------------

__global__ __launch_bounds__(256) void table_gemm(const unsigned short* __restrict__ iw1t,
                                                  const float* __restrict__ ib1,
                                                  const unsigned short* __restrict__ iw2t,
                                                  const float* __restrict__ ib2,
                                                  unsigned short* __restrict__ wtab) {
    __shared__ unsigned short Bs[16384];      // 32 KB
    __shared__ _Float16 Ts[64 * 136];         // 17 KB: ea staging, then t
    int l = blockIdx.y;
    int tid = threadIdx.x;
    int w = tid >> 6, lane = tid & 63, lr = lane & 15, lq = lane >> 4;
    int r0 = blockIdx.x * 64;
    int trow = w * 16;
    const float step  = DMAX / (float)(TBL - 1);
    const float sp    = 5.0f / 49.0f;
    const float coeff = -0.5f / (sp * sp);

    if (blockIdx.x == 0 && tid < H)
        wtab[(size_t)l * TSTR + (size_t)TBL * H + tid] = 0;

    for (int i = tid; i < 1024; i += 256) {
        int row = i >> 3, g = i & 7;
        int gs = (g ^ row) & 7;
        *(uint4*)&Bs[row * 64 + gs * 8] = *(const uint4*)&iw1t[(size_t)l * 8192 + i * 8];
    }
    for (int i = tid; i < 64 * 64; i += 256) {
        int r = i >> 6, g = i & 63;
        float d = (float)(r0 + r) * step;
        float dd = d - (float)g * sp;
        Ts[r * 136 + g] = (_Float16)((g < G) ? expf(coeff * dd * dd) : 0.0f);
    }
    float Cj[4];
    #pragma unroll
    for (int j = 0; j < 4; ++j) {
        float d = (float)(r0 + trow + 4 * lq + j) * step;
        Cj[j] = 0.5f * (cosf(d * (3.14159265358979323846f / 5.0f)) + 1.0f);
    }
    __syncthreads();
    half8 af[2];
    #pragma unroll
    for (int ks = 0; ks < 2; ++ks)
        af[ks] = *(const half8*)&Ts[(trow + lr) * 136 + ks * 32 + lq * 8];
    __syncthreads();

    #pragma unroll
    for (int n = 0; n < 8; ++n) {
        f32x4 acc = {0.f, 0.f, 0.f, 0.f};
        #pragma unroll
        for (int ks = 0; ks < 2; ++ks) {
            int row = n * 16 + lr, g = ks * 4 + lq;
            half8 bf = *(const half8*)&Bs[row * 64 + ((g ^ row) & 7) * 8];
            acc = __builtin_amdgcn_mfma_f32_16x16x32_f16(af[ks], bf, acc, 0, 0, 0);
        }
        float b = ib1[l * H + n * 16 + lr];
        #pragma unroll
        for (int j = 0; j < 4; ++j)
            Ts[(trow + 4 * lq + j) * 136 + n * 16 + lr] = (_Float16)sspf(acc[j] + b);
    }
    __syncthreads();
    stageB(iw2t + (size_t)l * 16384, Bs, tid);
    half8 tf[4];
    #pragma unroll
    for (int ks = 0; ks < 4; ++ks)
        tf[ks] = *(const half8*)&Ts[(trow + lr) * 136 + ks * 32 + lq * 8];
    __syncthreads();
    #pragma unroll
    for (int n = 0; n < 8; ++n) {
        f32x4 acc = {0.f, 0.f, 0.f, 0.f};
        #pragma unroll
        for (int ks = 0; ks < 4; ++ks) {
            half8 bf = *(const half8*)&Bs[bofs(n * 16 + lr, ks * 4 + lq)];
            acc = __builtin_amdgcn_mfma_f32_16x16x32_f16(tf[ks], bf, acc, 0, 0, 0);
        }
        float b = ib2[l * H + n * 16 + lr];
        #pragma unroll
        for (int j = 0; j < 4; ++j) {
            int row = r0 + trow + 4 * lq + j;
            wtab[(size_t)l * TSTR + (size_t)row * H + n * 16 + lr] =
                f2h((acc[j] + b) * Cj[j]);
        }
    }
}

// ---------------- fused h-init (f16) + x = f16(emb[z] @ B)  (layer 0) ----------------

__global__ __launch_bounds__(256) void gemm_hx(const int* __restrict__ z,
                                               const float* __restrict__ emb,
                                               const unsigned short* __restrict__ Bt,
                                               unsigned short* __restrict__ hout,
                                               unsigned short* __restrict__ xout, int M) {
    __shared__ unsigned short Bs[16384];
    int tid = threadIdx.x;
    int w = tid >> 6, lane = tid & 63, lr = lane & 15, lq = lane >> 4;
    int r0 = blockIdx.x * 64 + w * 16;
    stageB(Bt, Bs, tid);
    int row = min(r0 + lr, M - 1);
    const float* arow = emb + (size_t)z[row] * H;
    half8 af[4];
    #pragma unroll
    for (int ks = 0; ks < 4; ++ks) {
        float4 a = *(const float4*)(arow + ks * 32 + lq * 8);
        float4 b = *(const float4*)(arow + ks * 32 + lq * 8 + 4);
        af[ks] = cvt8(a, b);
        if (r0 + lr < M)
            *(half8*)&hout[(size_t)(r0 + lr) * H + ks * 32 + lq * 8] = af[ks];
    }
    __syncthreads();
    #pragma unroll
    for (int n = 0; n < 8; ++n) {
        f32x4 acc = {0.f, 0.f, 0.f, 0.f};
        #pragma unroll
        for (int ks = 0; ks < 4; ++ks) {
            half8 bf = *(const half8*)&Bs[bofs(n * 16 + lr, ks * 4 + lq)];
            acc = __builtin_amdgcn_mfma_f32_16x16x32_f16(af[ks], bf, acc, 0, 0, 0);
        }
        #pragma unroll
        for (int j = 0; j < 4; ++j) {
            int orow = r0 + 4 * lq + j;
            if (orow < M) xout[(size_t)orow * H + n * 16 + lr] = f2h(acc[j]);
        }
    }
}

// ---------------- fused node update (h in f16) ----------------
// pass A: t = ssp(Ain @ B1 + bias1)
// pass B: v = [h16res +] t @ B2 + bias2 -> hout (f16 if OUT16 else f32)
// pass C: xout = f16(v @ B3)            (if HASX)

template<int RES, int HASX, int OUT16>
__global__ __launch_bounds__(256) void node_fused(const unsigned short* __restrict__ Ain16,
                                                  const float* __restrict__ bias1,
                                                  const unsigned short* __restrict__ B1t,
                                                  const unsigned short* __restrict__ hres16,
                                                  unsigned short* __restrict__ hout16,
                                                  float* __restrict__ houtf,
                                                  const float* __restrict__ bias2,
                                                  const unsigned short* __restrict__ B2t,
                                                  const unsigned short* __restrict__ B3t,
                                                  unsigned short* __restrict__ xout, int M) {
    __shared__ unsigned short Bs[16384];
    __shared__ _Float16 Ts[64 * 136];
    int tid = threadIdx.x;
    int w = tid >> 6, lane = tid & 63, lr = lane & 15, lq = lane >> 4;
    int r0 = blockIdx.x * 64 + w * 16;
    int trow = w * 16;

    stageB(B1t, Bs, tid);
    half8 af[4];
    {
        const unsigned short* arow = Ain16 + (size_t)min(r0 + lr, M - 1) * H;
        #pragma unroll
        for (int ks = 0; ks < 4; ++ks)
            af[ks] = *(const half8*)(arow + ks * 32 + lq * 8);
    }
    __syncthreads();

    #pragma unroll
    for (int n = 0; n < 8; ++n) {
        f32x4 acc = {0.f, 0.f, 0.f, 0.f};
        #pragma unroll
        for (int ks = 0; ks < 4; ++ks) {
            half8 bf = *(const half8*)&Bs[bofs(n * 16 + lr, ks * 4 + lq)];
            acc = __builtin_amdgcn_mfma_f32_16x16x32_f16(af[ks], bf, acc, 0, 0, 0);
        }
        float b = bias1[n * 16 + lr];
        #pragma unroll
        for (int j = 0; j < 4; ++j)
            Ts[(trow + 4 * lq + j) * 136 + n * 16 + lr] = (_Float16)sspf(acc[j] + b);
    }
    __syncthreads();
    stageB(B2t, Bs, tid);
    half8 tf[4];
    #pragma unroll
    for (int ks = 0; ks < 4; ++ks)
        tf[ks] = *(const half8*)&Ts[(trow + lr) * 136 + ks * 32 + lq * 8];
    __syncthreads();

    #pragma unroll
    for (int n = 0; n < 8; ++n) {
        f32x4 acc = {0.f, 0.f, 0.f, 0.f};
        #pragma unroll
        for (int ks = 0; ks < 4; ++ks) {
            half8 bf = *(const half8*)&Bs[bofs(n * 16 + lr, ks * 4 + lq)];
            acc = __builtin_amdgcn_mfma_f32_16x16x32_f16(tf[ks], bf, acc, 0, 0, 0);
        }
        float b = bias2[n * 16 + lr];
        #pragma unroll
        for (int j = 0; j < 4; ++j) {
            int row = r0 + 4 * lq + j;
            float v = acc[j] + b;
            if (RES)
                v += (float)*(const _Float16*)&hres16[(size_t)min(row, M - 1) * H + n * 16 + lr];
            if (row < M) {
                if (OUT16) hout16[(size_t)row * H + n * 16 + lr] = f2h(v);
                else       houtf[(size_t)row * H + n * 16 + lr] = v;
            }
            if (HASX) Ts[(trow + 4 * lq + j) * 136 + n * 16 + lr] = (_Float16)v;
        }
    }

    if (HASX) {
        __syncthreads();
        stageB(B3t, Bs, tid);
        half8 hf[4];
        #pragma unroll
        for (int ks = 0; ks < 4; ++ks)
            hf[ks] = *(const half8*)&Ts[(trow + lr) * 136 + ks * 32 + lq * 8];
        __syncthreads();
        #pragma unroll
        for (int n = 0; n < 8; ++n) {
            f32x4 acc = {0.f, 0.f, 0.f, 0.f};
            #pragma unroll
            for (int ks = 0; ks < 4; ++ks) {
                half8 bf = *(const half8*)&Bs[bofs(n * 16 + lr, ks * 4 + lq)];
                acc = __builtin_amdgcn_mfma_f32_16x16x32_f16(hf[ks], bf, acc, 0, 0, 0);
            }
            #pragma unroll
            for (int j = 0; j < 4; ++j) {
                int row = r0 + 4 * lq + j;
                if (row < M) xout[(size_t)row * H + n * 16 + lr] = f2h(acc[j]);
            }
        }
    }
}

// ---------------- edge aggregation: 4 atoms/wave, 16 lanes x 8 feats, pipelined meta ----------------

__global__ __launch_bounds__(256) void edge_agg(const int* __restrict__ deg,
                                                const unsigned* __restrict__ meta,
                                                const unsigned short* __restrict__ x,
                                                const unsigned short* __restrict__ wt,
                                                unsigned short* __restrict__ agg) {
    int wv = threadIdx.x >> 6, ln = threadIdx.x & 63;
    int a = ln >> 4, fl = ln & 15;
    int i = (blockIdx.x << 4) + (wv << 2) + a;   // grid covers NA exactly
    int n8 = (min(deg[i], PAD) + 7) & ~7;
    const unsigned* mrow = meta + (size_t)i * PAD;
    int f8 = fl << 3;
    float acc[8] = {};
    unsigned mm[8];
    #pragma unroll
    for (int j = 0; j < 8; ++j) mm[j] = mrow[j];           // harmless if n8==0
    for (int p = 0; p < n8; p += 8) {
        uint4 xv[8], wv8[8];
        #pragma unroll
        for (int j = 0; j < 8; ++j) {
            unsigned s = mm[j] & 0xFFFFu, idx = mm[j] >> 16;
            xv[j]  = *(const uint4*)(x  + ((size_t)s   << 7) + f8);
            wv8[j] = *(const uint4*)(wt + ((size_t)idx << 7) + f8);
        }
        #pragma unroll
        for (int j = 0; j < 8; ++j) mm[j] = mrow[p + 8 + j];   // prefetch next chunk (slack-padded)
        #pragma unroll
        for (int j = 0; j < 8; ++j) {
            acc[0] += hlo(xv[j].x) * hlo(wv8[j].x);
            acc[1] += hhi(xv[j].x) * hhi(wv8[j].x);
            acc[2] += hlo(xv[j].y) * hlo(wv8[j].y);
            acc[3] += hhi(xv[j].y) * hhi(wv8[j].y);
            acc[4] += hlo(xv[j].z) * hlo(wv8[j].z);
            acc[5] += hhi(xv[j].z) * hhi(wv8[j].z);
            acc[6] += hlo(xv[j].w) * hlo(wv8[j].w);
            acc[7] += hhi(xv[j].w) * hhi(wv8[j].w);
        }
    }
    uint4 ov;
    ov.x = (unsigned)f2h(acc[0]) | ((unsigned)f2h(acc[1]) << 16);
    ov.y = (unsigned)f2h(acc[2]) | ((unsigned)f2h(acc[3]) << 16);
    ov.z = (unsigned)f2h(acc[4]) | ((unsigned)f2h(acc[5]) << 16);
    ov.w = (unsigned)f2h(acc[6]) | ((unsigned)f2h(acc[7]) << 16);
    *(uint4*)&agg[((size_t)i << 7) + f8] = ov;
}

// ---------------- readout ----------------

__global__ void mol_bounds(const int* __restrict__ a2c, const int* __restrict__ c2m,
                           int* __restrict__ ms, int* __restrict__ me) {
    int i = blockIdx.x * 256 + threadIdx.x;
    if (i >= NA) return;
    int m = c2m[a2c[i]];
    int mp = (i == 0) ? -1 : c2m[a2c[i - 1]];
    if (m != mp) ms[m] = i;
    int mn = (i == NA - 1) ? -1 : c2m[a2c[i + 1]];
    if (m != mn) me[m] = i + 1;
}

__global__ __launch_bounds__(512) void mol_sum(const int* __restrict__ ms, const int* __restrict__ me,
                                               const float* __restrict__ h2buf, float* __restrict__ mol) {
    __shared__ float red[4][128];
    int m = blockIdx.x;
    int f = threadIdx.x & 127, q = threadIdx.x >> 7;
    float acc = 0.f;
    int e0 = ms[m], e1 = me[m];
    for (int i = e0 + q; i < e1; i += 4) acc += h2buf[((size_t)i << 7) + f];
    red[q][f] = acc;
    __syncthreads();
    if (q == 0) mol[(m << 7) + f] = red[0][f] + red[1][f] + red[2][f] + red[3][f];
}

__global__ void final_mlp(const float* __restrict__ mol, const float* __restrict__ h1w,
                          const float* __restrict__ h1b, const float* __restrict__ h2w,
                          const float* __restrict__ h2b, float* __restrict__ out) {
    int m = blockIdx.x;
    int j = threadIdx.x;
    float acc = h1b[j];
    for (int k = 0; k < H; ++k) acc += mol[(m << 7) + k] * h1w[k * 64 + j];
    float hv = sspf(acc) * h2w[j];
    #pragma unroll
    for (int off = 32; off > 0; off >>= 1) hv += __shfl_down(hv, off);
    if (j == 0) out[m] = hv + h2b[0];
}

} // namespace

extern "C" void kernel_launch(void* const* d_in, const int* in_sizes, int n_in,
                              void* d_out, int out_size, void* d_ws, size_t ws_size,
                              hipStream_t stream) {
    const int*   z    = (const int*)d_in[0];
    const float* pos  = (const float*)d_in[1];
    const int*   ei   = (const int*)d_in[2];
    const int*   a2c  = (const int*)d_in[3];
    const int*   c2m  = (const int*)d_in[4];
    const float* emb  = (const float*)d_in[5];
    const float* iw1  = (const float*)d_in[6];
    const float* ib1  = (const float*)d_in[7];
    const float* iw2  = (const float*)d_in[8];
    const float* ib2  = (const float*)d_in[9];
    const float* il1  = (const float*)d_in[10];
    const float* il2w = (const float*)d_in[11];
    const float* il2b = (const float*)d_in[12];
    const float* ilw  = (const float*)d_in[13];
    const float* ilb  = (const float*)d_in[14];
    const float* l1w  = (const float*)d_in[15];
    const float* l1b  = (const float*)d_in[16];
    const float* l2w  = (const float*)d_in[17];
    const float* l2b  = (const float*)d_in[18];
    const float* h1w  = (const float*)d_in[19];
    const float* h1b  = (const float*)d_in[20];
    const float* h2w  = (const float*)d_in[21];
    const float* h2b  = (const float*)d_in[22];
    float* out = (float*)d_out;
    (void)in_sizes; (void)n_in; (void)out_size; (void)ws_size;

    char* base = (char*)d_ws;
    size_t off = 0;
    auto carve = [&](size_t bytes) -> char* {
        char* p = base + off;
        off += (bytes + 255) & ~(size_t)255;
        return p;
    };
    unsigned short* hb    = (unsigned short*)carve((size_t)NA * H * 2);
    unsigned short* xb    = (unsigned short*)carve((size_t)NA * H * 2);
    float*          agg   = (float*)carve((size_t)NA * H * 4);   // f16 during loop, f32 at end
    unsigned short* wtab  = (unsigned short*)carve((size_t)L * TSTR * 2);
    unsigned*       meta  = (unsigned*)carve(((size_t)NA * PAD + 16) * 4);  // +16 prefetch slack
    int*            counts= (int*)carve((size_t)NA * 4);
    int*            ms    = (int*)carve((size_t)NM * 4);
    int*            me    = (int*)carve((size_t)NM * 4);
    float*          mol   = (float*)carve((size_t)NM * H * 4);
    unsigned short* il1t  = (unsigned short*)carve((size_t)L * H * H * 2);
    unsigned short* il2wt = (unsigned short*)carve((size_t)L * H * H * 2);
    unsigned short* ilwt  = (unsigned short*)carve((size_t)L * H * H * 2);
    unsigned short* iw2t  = (unsigned short*)carve((size_t)L * H * H * 2);
    unsigned short* l1wt  = (unsigned short*)carve((size_t)H * H * 2);
    unsigned short* l2wt  = (unsigned short*)carve((size_t)H * H * 2);
    unsigned short* iw1t  = (unsigned short*)carve((size_t)L * H * 64 * 2);
    unsigned short* aggh  = (unsigned short*)agg;

    hipMemsetAsync(counts, 0, (size_t)NA * 4, stream);
    edge_build<<<NE / 256, 256, 0, stream>>>(pos, ei, counts, meta);
    meta_pad<<<(NA + 255) / 256, 256, 0, stream>>>(counts, meta);

    prep_weights<<<dim3(64, 32), 256, 0, stream>>>(il1, il2w, ilw, iw2, l1w, l2w, iw1,
                                                   il1t, il2wt, ilwt, iw2t, l1wt, l2wt, iw1t);
    table_gemm<<<dim3(TBL / 64, L), 256, 0, stream>>>(iw1t, ib1, iw2t, ib2, wtab);

    const int NG = (NA + 63) / 64;   // 782
    gemm_hx<<<NG, 256, 0, stream>>>(z, emb, il1t, hb, xb, NA);
    for (int k = 0; k < L; ++k) {
        edge_agg<<<NA / 16, 256, 0, stream>>>(counts, meta, xb,
                                              wtab + (size_t)k * TSTR, aggh);
        if (k < L - 1) {
            node_fused<1, 1, 1><<<NG, 256, 0, stream>>>(aggh,
                il2b + (size_t)k * H, il2wt + (size_t)k * H * H,
                hb, hb, nullptr, ilb + (size_t)k * H, ilwt + (size_t)k * H * H,
                il1t + (size_t)(k + 1) * H * H, xb, NA);
        } else {
            node_fused<1, 0, 1><<<NG, 256, 0, stream>>>(aggh,
                il2b + (size_t)k * H, il2wt + (size_t)k * H * H,
                hb, hb, nullptr, ilb + (size_t)k * H, ilwt + (size_t)k * H * H,
                nullptr, nullptr, NA);
        }
    }
    // final: agg(f32) = ssp(h@l1w+l1b)@l2w+l2b
    node_fused<0, 0, 0><<<NG, 256, 0, stream>>>(hb, l1b, l1wt, nullptr, nullptr, agg,
                                                l2b, l2wt, nullptr, nullptr, NA);

    hipMemsetAsync(ms, 0, (size_t)NM * 4, stream);
    hipMemsetAsync(me, 0, (size_t)NM * 4, stream);
    mol_bounds<<<(NA + 255) / 256, 256, 0, stream>>>(a2c, c2m, ms, me);
    mol_sum<<<NM, 512, 0, stream>>>(ms, me, agg, mol);
    final_mlp<<<NM, 64, 0, stream>>>(mol, h1w, h1b, h2w, h2b, out);
}

// Round 10
// 821.618 us; speedup vs baseline: 1.1614x; 1.0034x over previous
//
#include <hip/hip_runtime.h>
#include <math.h>

namespace {

constexpr int NA  = 50000;
constexpr int NE  = 1600000;
constexpr int NM  = 500;
constexpr int H   = 128;
constexpr int G   = 50;
constexpr int L   = 6;
constexpr int TBL = 8192;
constexpr int TSTR = (TBL + 1) * H;     // per-layer wtab stride (row TBL = zero row)
constexpr int PAD = 80;
constexpr float DMAX = 5.6f;            // beyond 5.6 the Gaussian envelope is <3e-8; do NOT lower
                                        // (C(d) rises again past d=5 — round 9 lesson)

typedef _Float16 half8 __attribute__((ext_vector_type(8)));
typedef float f32x4 __attribute__((ext_vector_type(4)));
struct hpair { _Float16 x, y; };

__device__ __forceinline__ float sspf(float v) {
    return fmaxf(v, 0.0f) + log1pf(expf(-fabsf(v))) - 0.6931471805599453f;
}
__device__ __forceinline__ unsigned short f2h(float f) {
    _Float16 h = (_Float16)f;
    return __builtin_bit_cast(unsigned short, h);
}
__device__ __forceinline__ half8 cvt8(float4 a, float4 b) {
    half8 r;
    r[0] = (_Float16)a.x; r[1] = (_Float16)a.y; r[2] = (_Float16)a.z; r[3] = (_Float16)a.w;
    r[4] = (_Float16)b.x; r[5] = (_Float16)b.y; r[6] = (_Float16)b.z; r[7] = (_Float16)b.w;
    return r;
}
__device__ __forceinline__ float hlo(unsigned v) {
    return (float)__builtin_bit_cast(hpair, v).x;
}
__device__ __forceinline__ float hhi(unsigned v) {
    return (float)__builtin_bit_cast(hpair, v).y;
}
// B^T LDS granule offset with XOR swizzle for 128-u16 row pitch (G4)
__device__ __forceinline__ int bofs(int nrow, int g) {   // g = 16B granule 0..15
    int gs = (g & 8) | ((g ^ nrow) & 7);
    return nrow * 128 + gs * 8;
}
__device__ __forceinline__ void stageB(const unsigned short* __restrict__ Bt,
                                       unsigned short* Bs, int tid) {
    for (int i = tid; i < 2048; i += 256) {
        int row = i >> 4, g = i & 15;
        *(uint4*)&Bs[bofs(row, g)] = *(const uint4*)&Bt[i * 8];
    }
}

// ---------------- preprocessing: one-pass padded-CSR build ----------------

__global__ void edge_build(const float* __restrict__ pos, const int* __restrict__ ei,
                           int* __restrict__ counts, unsigned* __restrict__ meta) {
    int e = blockIdx.x * 256 + threadIdx.x;
    if (e >= NE) return;
    int s = ei[e], t = ei[NE + e];
    float dx = pos[3*s]   - pos[3*t];
    float dy = pos[3*s+1] - pos[3*t+1];
    float dz = pos[3*s+2] - pos[3*t+2];
    float d = sqrtf(dx*dx + dy*dy + dz*dz + 1e-12f);
    float u = d * ((float)(TBL - 1) / DMAX);
    if (u < (float)(TBL - 1)) {
        int idx = (int)(u + 0.5f);
        int r = atomicAdd(&counts[t], 1);
        if (r < PAD) meta[(size_t)t * PAD + r] = (unsigned)s | ((unsigned)idx << 16);
    }
}

// pad each row to a multiple of 8 with (s=0, idx=TBL) -> gathers the zero wtab row
__global__ void meta_pad(const int* __restrict__ deg, unsigned* __restrict__ meta) {
    int i = blockIdx.x * 256 + threadIdx.x;
    if (i >= NA) return;
    int n = min(deg[i], PAD);
    int n8 = (n + 7) & ~7;
    const unsigned pv = (unsigned)TBL << 16;
    for (int r = n; r < n8; ++r) meta[(size_t)i * PAD + r] = pv;
}

// ---------------- one-launch weight prep: f32 [K][N] -> f16 B^T [N][K] (+ padded iw1) ----------------

__global__ void prep_weights(const float* __restrict__ il1, const float* __restrict__ il2w,
                             const float* __restrict__ ilw, const float* __restrict__ iw2,
                             const float* __restrict__ l1w, const float* __restrict__ l2w,
                             const float* __restrict__ iw1,
                             unsigned short* __restrict__ il1t, unsigned short* __restrict__ il2wt,
                             unsigned short* __restrict__ ilwt, unsigned short* __restrict__ iw2t,
                             unsigned short* __restrict__ l1wt, unsigned short* __restrict__ l2wt,
                             unsigned short* __restrict__ iw1t) {
    int m = blockIdx.y;
    int e = blockIdx.x * 256 + threadIdx.x;
    if (m < 26) {
        const float* src; unsigned short* dst;
        if (m < 6)       { src = il1  + (size_t)m * 16384;        dst = il1t  + (size_t)m * 16384; }
        else if (m < 12) { src = il2w + (size_t)(m - 6) * 16384;  dst = il2wt + (size_t)(m - 6) * 16384; }
        else if (m < 18) { src = ilw  + (size_t)(m - 12) * 16384; dst = ilwt  + (size_t)(m - 12) * 16384; }
        else if (m < 24) { src = iw2  + (size_t)(m - 18) * 16384; dst = iw2t  + (size_t)(m - 18) * 16384; }
        else if (m == 24){ src = l1w; dst = l1wt; }
        else             { src = l2w; dst = l2wt; }
        int n = e >> 7, k = e & 127;
        dst[e] = f2h(src[k * 128 + n]);
    } else {
        int l = m - 26;
        if (e < 8192) {
            int n = e >> 6, k = e & 63;
            float v = (k < G) ? iw1[(size_t)l * G * H + k * H + n] : 0.0f;
            iw1t[(size_t)l * 8192 + e] = f2h(v);
        }
    }
}

// ---------------- filter tables via MFMA: grid (TBL/64, L) ----------------

__global__ __launch_bounds__(256) void table_gemm(const unsigned short* __restrict__ iw1t,
                                                  const float* __restrict__ ib1,
                                                  const unsigned short* __restrict__ iw2t,
                                                  const float* __restrict__ ib2,
                                                  unsigned short* __restrict__ wtab) {
    __shared__ unsigned short Bs[16384];      // 32 KB
    __shared__ _Float16 Ts[64 * 136];         // 17 KB: ea staging, then t
    int l = blockIdx.y;
    int tid = threadIdx.x;
    int w = tid >> 6, lane = tid & 63, lr = lane & 15, lq = lane >> 4;
    int r0 = blockIdx.x * 64;
    int trow = w * 16;
    const float step  = DMAX / (float)(TBL - 1);
    const float sp    = 5.0f / 49.0f;
    const float coeff = -0.5f / (sp * sp);

    if (blockIdx.x == 0 && tid < H)
        wtab[(size_t)l * TSTR + (size_t)TBL * H + tid] = 0;

    for (int i = tid; i < 1024; i += 256) {
        int row = i >> 3, g = i & 7;
        int gs = (g ^ row) & 7;
        *(uint4*)&Bs[row * 64 + gs * 8] = *(const uint4*)&iw1t[(size_t)l * 8192 + i * 8];
    }
    for (int i = tid; i < 64 * 64; i += 256) {
        int r = i >> 6, g = i & 63;
        float d = (float)(r0 + r) * step;
        float dd = d - (float)g * sp;
        Ts[r * 136 + g] = (_Float16)((g < G) ? expf(coeff * dd * dd) : 0.0f);
    }
    float Cj[4];
    #pragma unroll
    for (int j = 0; j < 4; ++j) {
        float d = (float)(r0 + trow + 4 * lq + j) * step;
        Cj[j] = 0.5f * (cosf(d * (3.14159265358979323846f / 5.0f)) + 1.0f);
    }
    __syncthreads();
    half8 af[2];
    #pragma unroll
    for (int ks = 0; ks < 2; ++ks)
        af[ks] = *(const half8*)&Ts[(trow + lr) * 136 + ks * 32 + lq * 8];
    __syncthreads();

    #pragma unroll
    for (int n = 0; n < 8; ++n) {
        f32x4 acc = {0.f, 0.f, 0.f, 0.f};
        #pragma unroll
        for (int ks = 0; ks < 2; ++ks) {
            int row = n * 16 + lr, g = ks * 4 + lq;
            half8 bf = *(const half8*)&Bs[row * 64 + ((g ^ row) & 7) * 8];
            acc = __builtin_amdgcn_mfma_f32_16x16x32_f16(af[ks], bf, acc, 0, 0, 0);
        }
        float b = ib1[l * H + n * 16 + lr];
        #pragma unroll
        for (int j = 0; j < 4; ++j)
            Ts[(trow + 4 * lq + j) * 136 + n * 16 + lr] = (_Float16)sspf(acc[j] + b);
    }
    __syncthreads();
    stageB(iw2t + (size_t)l * 16384, Bs, tid);
    half8 tf[4];
    #pragma unroll
    for (int ks = 0; ks < 4; ++ks)
        tf[ks] = *(const half8*)&Ts[(trow + lr) * 136 + ks * 32 + lq * 8];
    __syncthreads();
    #pragma unroll
    for (int n = 0; n < 8; ++n) {
        f32x4 acc = {0.f, 0.f, 0.f, 0.f};
        #pragma unroll
        for (int ks = 0; ks < 4; ++ks) {
            half8 bf = *(const half8*)&Bs[bofs(n * 16 + lr, ks * 4 + lq)];
            acc = __builtin_amdgcn_mfma_f32_16x16x32_f16(tf[ks], bf, acc, 0, 0, 0);
        }
        float b = ib2[l * H + n * 16 + lr];
        #pragma unroll
        for (int j = 0; j < 4; ++j) {
            int row = r0 + trow + 4 * lq + j;
            wtab[(size_t)l * TSTR + (size_t)row * H + n * 16 + lr] =
                f2h((acc[j] + b) * Cj[j]);
        }
    }
}

// ---------------- fused h-init (f16) + x = f16(emb[z] @ B)  (layer 0) ----------------

__global__ __launch_bounds__(256) void gemm_hx(const int* __restrict__ z,
                                               const float* __restrict__ emb,
                                               const unsigned short* __restrict__ Bt,
                                               unsigned short* __restrict__ hout,
                                               unsigned short* __restrict__ xout, int M) {
    __shared__ unsigned short Bs[16384];
    int tid = threadIdx.x;
    int w = tid >> 6, lane = tid & 63, lr = lane & 15, lq = lane >> 4;
    int r0 = blockIdx.x * 64 + w * 16;
    stageB(Bt, Bs, tid);
    int row = min(r0 + lr, M - 1);
    const float* arow = emb + (size_t)z[row] * H;
    half8 af[4];
    #pragma unroll
    for (int ks = 0; ks < 4; ++ks) {
        float4 a = *(const float4*)(arow + ks * 32 + lq * 8);
        float4 b = *(const float4*)(arow + ks * 32 + lq * 8 + 4);
        af[ks] = cvt8(a, b);
        if (r0 + lr < M)
            *(half8*)&hout[(size_t)(r0 + lr) * H + ks * 32 + lq * 8] = af[ks];
    }
    __syncthreads();
    #pragma unroll
    for (int n = 0; n < 8; ++n) {
        f32x4 acc = {0.f, 0.f, 0.f, 0.f};
        #pragma unroll
        for (int ks = 0; ks < 4; ++ks) {
            half8 bf = *(const half8*)&Bs[bofs(n * 16 + lr, ks * 4 + lq)];
            acc = __builtin_amdgcn_mfma_f32_16x16x32_f16(af[ks], bf, acc, 0, 0, 0);
        }
        #pragma unroll
        for (int j = 0; j < 4; ++j) {
            int orow = r0 + 4 * lq + j;
            if (orow < M) xout[(size_t)orow * H + n * 16 + lr] = f2h(acc[j]);
        }
    }
}

// ---------------- fused layer step: edge-gather + 3 GEMMs, one launch per layer ----------------
// x is DOUBLE-BUFFERED across layers: gather reads xin, pass C writes xout (different buffer)
// -> no cross-block RAW/WAR within a launch (round-9 race fix).

template<int HASX>
__global__ __launch_bounds__(256) void layer_step(const int* __restrict__ deg,
                                                  const unsigned* __restrict__ meta,
                                                  const unsigned short* __restrict__ xin,
                                                  const unsigned short* __restrict__ wt,
                                                  const float* __restrict__ bias1,
                                                  const unsigned short* __restrict__ B1t,
                                                  const float* __restrict__ bias2,
                                                  const unsigned short* __restrict__ B2t,
                                                  const unsigned short* __restrict__ B3t,
                                                  unsigned short* __restrict__ hio,
                                                  unsigned short* __restrict__ xout, int M) {
    __shared__ unsigned short Bs[16384];
    __shared__ _Float16 Ts[64 * 136];
    int tid = threadIdx.x;
    int w = tid >> 6, lane = tid & 63, lr = lane & 15, lq = lane >> 4;
    int r0blk = blockIdx.x * 64;
    int r0 = r0blk + w * 16;
    int trow = w * 16;

    stageB(B1t, Bs, tid);      // overlap weight staging with the gather below

    // ---- edge gather -> Ts (agg, f16). 16 lanes/atom x 8 feats, 4 atom-batches ----
    {
        int fl = tid & 15, f8 = fl << 3;
        #pragma unroll
        for (int b = 0; b < 4; ++b) {
            int al = (b << 4) + (tid >> 4);
            int ga = r0blk + al;
            float acc[8] = {};
            if (ga < M) {
                int n8 = (min(deg[ga], PAD) + 7) & ~7;
                const unsigned* mrow = meta + (size_t)ga * PAD;
                for (int p = 0; p < n8; p += 8) {
                    unsigned mm[8];
                    #pragma unroll
                    for (int j = 0; j < 8; ++j) mm[j] = mrow[p + j];
                    uint4 xv[8], wv8[8];
                    #pragma unroll
                    for (int j = 0; j < 8; ++j) {
                        unsigned s = mm[j] & 0xFFFFu, idx = mm[j] >> 16;
                        xv[j]  = *(const uint4*)(xin + ((size_t)s   << 7) + f8);
                        wv8[j] = *(const uint4*)(wt  + ((size_t)idx << 7) + f8);
                    }
                    #pragma unroll
                    for (int j = 0; j < 8; ++j) {
                        acc[0] += hlo(xv[j].x) * hlo(wv8[j].x);
                        acc[1] += hhi(xv[j].x) * hhi(wv8[j].x);
                        acc[2] += hlo(xv[j].y) * hlo(wv8[j].y);
                        acc[3] += hhi(xv[j].y) * hhi(wv8[j].y);
                        acc[4] += hlo(xv[j].z) * hlo(wv8[j].z);
                        acc[5] += hhi(xv[j].z) * hhi(wv8[j].z);
                        acc[6] += hlo(xv[j].w) * hlo(wv8[j].w);
                        acc[7] += hhi(xv[j].w) * hhi(wv8[j].w);
                    }
                }
            }
            half8 hv;
            #pragma unroll
            for (int e = 0; e < 8; ++e) hv[e] = (_Float16)acc[e];
            *(half8*)&Ts[al * 136 + f8] = hv;
        }
    }
    __syncthreads();

    half8 af[4];
    #pragma unroll
    for (int ks = 0; ks < 4; ++ks)
        af[ks] = *(const half8*)&Ts[(trow + lr) * 136 + ks * 32 + lq * 8];
    __syncthreads();

    // ---- pass A: t = ssp(agg @ B1 + b1) -> Ts ----
    #pragma unroll
    for (int n = 0; n < 8; ++n) {
        f32x4 acc = {0.f, 0.f, 0.f, 0.f};
        #pragma unroll
        for (int ks = 0; ks < 4; ++ks) {
            half8 bf = *(const half8*)&Bs[bofs(n * 16 + lr, ks * 4 + lq)];
            acc = __builtin_amdgcn_mfma_f32_16x16x32_f16(af[ks], bf, acc, 0, 0, 0);
        }
        float b = bias1[n * 16 + lr];
        #pragma unroll
        for (int j = 0; j < 4; ++j)
            Ts[(trow + 4 * lq + j) * 136 + n * 16 + lr] = (_Float16)sspf(acc[j] + b);
    }
    __syncthreads();
    stageB(B2t, Bs, tid);
    half8 tf[4];
    #pragma unroll
    for (int ks = 0; ks < 4; ++ks)
        tf[ks] = *(const half8*)&Ts[(trow + lr) * 136 + ks * 32 + lq * 8];
    __syncthreads();

    // ---- pass B: v = h + t @ B2 + b2 -> h (and Ts if HASX) ----
    #pragma unroll
    for (int n = 0; n < 8; ++n) {
        f32x4 acc = {0.f, 0.f, 0.f, 0.f};
        #pragma unroll
        for (int ks = 0; ks < 4; ++ks) {
            half8 bf = *(const half8*)&Bs[bofs(n * 16 + lr, ks * 4 + lq)];
            acc = __builtin_amdgcn_mfma_f32_16x16x32_f16(tf[ks], bf, acc, 0, 0, 0);
        }
        float b = bias2[n * 16 + lr];
        #pragma unroll
        for (int j = 0; j < 4; ++j) {
            int row = r0 + 4 * lq + j;
            float v = acc[j] + b +
                (float)*(const _Float16*)&hio[(size_t)min(row, M - 1) * H + n * 16 + lr];
            if (row < M) hio[(size_t)row * H + n * 16 + lr] = f2h(v);
            if (HASX) Ts[(trow + 4 * lq + j) * 136 + n * 16 + lr] = (_Float16)v;
        }
    }

    // ---- pass C: xout = f16(v @ B3) ----
    if (HASX) {
        __syncthreads();
        stageB(B3t, Bs, tid);
        half8 hf[4];
        #pragma unroll
        for (int ks = 0; ks < 4; ++ks)
            hf[ks] = *(const half8*)&Ts[(trow + lr) * 136 + ks * 32 + lq * 8];
        __syncthreads();
        #pragma unroll
        for (int n = 0; n < 8; ++n) {
            f32x4 acc = {0.f, 0.f, 0.f, 0.f};
            #pragma unroll
            for (int ks = 0; ks < 4; ++ks) {
                half8 bf = *(const half8*)&Bs[bofs(n * 16 + lr, ks * 4 + lq)];
                acc = __builtin_amdgcn_mfma_f32_16x16x32_f16(hf[ks], bf, acc, 0, 0, 0);
            }
            #pragma unroll
            for (int j = 0; j < 4; ++j) {
                int row = r0 + 4 * lq + j;
                if (row < M) xout[(size_t)row * H + n * 16 + lr] = f2h(acc[j]);
            }
        }
    }
}

// ---------------- final pair: out32 = ssp(h@B1+b1)@B2+b2 ----------------

__global__ __launch_bounds__(256) void final_pair(const unsigned short* __restrict__ Ain16,
                                                  const float* __restrict__ bias1,
                                                  const unsigned short* __restrict__ B1t,
                                                  const float* __restrict__ bias2,
                                                  const unsigned short* __restrict__ B2t,
                                                  float* __restrict__ outf, int M) {
    __shared__ unsigned short Bs[16384];
    __shared__ _Float16 Ts[64 * 136];
    int tid = threadIdx.x;
    int w = tid >> 6, lane = tid & 63, lr = lane & 15, lq = lane >> 4;
    int r0 = blockIdx.x * 64 + w * 16;
    int trow = w * 16;

    stageB(B1t, Bs, tid);
    half8 af[4];
    {
        const unsigned short* arow = Ain16 + (size_t)min(r0 + lr, M - 1) * H;
        #pragma unroll
        for (int ks = 0; ks < 4; ++ks)
            af[ks] = *(const half8*)(arow + ks * 32 + lq * 8);
    }
    __syncthreads();

    #pragma unroll
    for (int n = 0; n < 8; ++n) {
        f32x4 acc = {0.f, 0.f, 0.f, 0.f};
        #pragma unroll
        for (int ks = 0; ks < 4; ++ks) {
            half8 bf = *(const half8*)&Bs[bofs(n * 16 + lr, ks * 4 + lq)];
            acc = __builtin_amdgcn_mfma_f32_16x16x32_f16(af[ks], bf, acc, 0, 0, 0);
        }
        float b = bias1[n * 16 + lr];
        #pragma unroll
        for (int j = 0; j < 4; ++j)
            Ts[(trow + 4 * lq + j) * 136 + n * 16 + lr] = (_Float16)sspf(acc[j] + b);
    }
    __syncthreads();
    stageB(B2t, Bs, tid);
    half8 tf[4];
    #pragma unroll
    for (int ks = 0; ks < 4; ++ks)
        tf[ks] = *(const half8*)&Ts[(trow + lr) * 136 + ks * 32 + lq * 8];
    __syncthreads();

    #pragma unroll
    for (int n = 0; n < 8; ++n) {
        f32x4 acc = {0.f, 0.f, 0.f, 0.f};
        #pragma unroll
        for (int ks = 0; ks < 4; ++ks) {
            half8 bf = *(const half8*)&Bs[bofs(n * 16 + lr, ks * 4 + lq)];
            acc = __builtin_amdgcn_mfma_f32_16x16x32_f16(tf[ks], bf, acc, 0, 0, 0);
        }
        float b = bias2[n * 16 + lr];
        #pragma unroll
        for (int j = 0; j < 4; ++j) {
            int row = r0 + 4 * lq + j;
            if (row < M) outf[(size_t)row * H + n * 16 + lr] = acc[j] + b;
        }
    }
}

// ---------------- readout ----------------

__global__ void mol_bounds(const int* __restrict__ a2c, const int* __restrict__ c2m,
                           int* __restrict__ ms, int* __restrict__ me) {
    int i = blockIdx.x * 256 + threadIdx.x;
    if (i >= NA) return;
    int m = c2m[a2c[i]];
    int mp = (i == 0) ? -1 : c2m[a2c[i - 1]];
    if (m != mp) ms[m] = i;
    int mn = (i == NA - 1) ? -1 : c2m[a2c[i + 1]];
    if (m != mn) me[m] = i + 1;
}

__global__ __launch_bounds__(512) void mol_sum(const int* __restrict__ ms, const int* __restrict__ me,
                                               const float* __restrict__ h2buf, float* __restrict__ mol) {
    __shared__ float red[4][128];
    int m = blockIdx.x;
    int f = threadIdx.x & 127, q = threadIdx.x >> 7;
    float acc = 0.f;
    int e0 = ms[m], e1 = me[m];
    for (int i = e0 + q; i < e1; i += 4) acc += h2buf[((size_t)i << 7) + f];
    red[q][f] = acc;
    __syncthreads();
    if (q == 0) mol[(m << 7) + f] = red[0][f] + red[1][f] + red[2][f] + red[3][f];
}

__global__ void final_mlp(const float* __restrict__ mol, const float* __restrict__ h1w,
                          const float* __restrict__ h1b, const float* __restrict__ h2w,
                          const float* __restrict__ h2b, float* __restrict__ out) {
    int m = blockIdx.x;
    int j = threadIdx.x;
    float acc = h1b[j];
    for (int k = 0; k < H; ++k) acc += mol[(m << 7) + k] * h1w[k * 64 + j];
    float hv = sspf(acc) * h2w[j];
    #pragma unroll
    for (int off = 32; off > 0; off >>= 1) hv += __shfl_down(hv, off);
    if (j == 0) out[m] = hv + h2b[0];
}

} // namespace

extern "C" void kernel_launch(void* const* d_in, const int* in_sizes, int n_in,
                              void* d_out, int out_size, void* d_ws, size_t ws_size,
                              hipStream_t stream) {
    const int*   z    = (const int*)d_in[0];
    const float* pos  = (const float*)d_in[1];
    const int*   ei   = (const int*)d_in[2];
    const int*   a2c  = (const int*)d_in[3];
    const int*   c2m  = (const int*)d_in[4];
    const float* emb  = (const float*)d_in[5];
    const float* iw1  = (const float*)d_in[6];
    const float* ib1  = (const float*)d_in[7];
    const float* iw2  = (const float*)d_in[8];
    const float* ib2  = (const float*)d_in[9];
    const float* il1  = (const float*)d_in[10];
    const float* il2w = (const float*)d_in[11];
    const float* il2b = (const float*)d_in[12];
    const float* ilw  = (const float*)d_in[13];
    const float* ilb  = (const float*)d_in[14];
    const float* l1w  = (const float*)d_in[15];
    const float* l1b  = (const float*)d_in[16];
    const float* l2w  = (const float*)d_in[17];
    const float* l2b  = (const float*)d_in[18];
    const float* h1w  = (const float*)d_in[19];
    const float* h1b  = (const float*)d_in[20];
    const float* h2w  = (const float*)d_in[21];
    const float* h2b  = (const float*)d_in[22];
    float* out = (float*)d_out;
    (void)in_sizes; (void)n_in; (void)out_size; (void)ws_size;

    char* base = (char*)d_ws;
    size_t off = 0;
    auto carve = [&](size_t bytes) -> char* {
        char* p = base + off;
        off += (bytes + 255) & ~(size_t)255;
        return p;
    };
    unsigned short* hb    = (unsigned short*)carve((size_t)NA * H * 2);
    unsigned short* xb0   = (unsigned short*)carve((size_t)NA * H * 2);
    unsigned short* xb1   = (unsigned short*)carve((size_t)NA * H * 2);
    float*          h2f   = (float*)carve((size_t)NA * H * 4);
    unsigned short* wtab  = (unsigned short*)carve((size_t)L * TSTR * 2);
    unsigned*       meta  = (unsigned*)carve(((size_t)NA * PAD + 16) * 4);
    int*            counts= (int*)carve((size_t)NA * 4);
    int*            ms    = (int*)carve((size_t)NM * 4);
    int*            me    = (int*)carve((size_t)NM * 4);
    float*          mol   = (float*)carve((size_t)NM * H * 4);
    unsigned short* il1t  = (unsigned short*)carve((size_t)L * H * H * 2);
    unsigned short* il2wt = (unsigned short*)carve((size_t)L * H * H * 2);
    unsigned short* ilwt  = (unsigned short*)carve((size_t)L * H * H * 2);
    unsigned short* iw2t  = (unsigned short*)carve((size_t)L * H * H * 2);
    unsigned short* l1wt  = (unsigned short*)carve((size_t)H * H * 2);
    unsigned short* l2wt  = (unsigned short*)carve((size_t)H * H * 2);
    unsigned short* iw1t  = (unsigned short*)carve((size_t)L * H * 64 * 2);

    hipMemsetAsync(counts, 0, (size_t)NA * 4, stream);
    edge_build<<<NE / 256, 256, 0, stream>>>(pos, ei, counts, meta);
    meta_pad<<<(NA + 255) / 256, 256, 0, stream>>>(counts, meta);

    prep_weights<<<dim3(64, 32), 256, 0, stream>>>(il1, il2w, ilw, iw2, l1w, l2w, iw1,
                                                   il1t, il2wt, ilwt, iw2t, l1wt, l2wt, iw1t);
    table_gemm<<<dim3(TBL / 64, L), 256, 0, stream>>>(iw1t, ib1, iw2t, ib2, wtab);

    const int NG = (NA + 63) / 64;   // 782
    gemm_hx<<<NG, 256, 0, stream>>>(z, emb, il1t, hb, xb0, NA);
    unsigned short* xbuf[2] = { xb0, xb1 };
    for (int k = 0; k < L; ++k) {
        unsigned short* xin  = xbuf[k & 1];
        unsigned short* xout = xbuf[(k + 1) & 1];
        if (k < L - 1) {
            layer_step<1><<<NG, 256, 0, stream>>>(counts, meta, xin, wtab + (size_t)k * TSTR,
                il2b + (size_t)k * H, il2wt + (size_t)k * H * H,
                ilb + (size_t)k * H, ilwt + (size_t)k * H * H,
                il1t + (size_t)(k + 1) * H * H, hb, xout, NA);
        } else {
            layer_step<0><<<NG, 256, 0, stream>>>(counts, meta, xin, wtab + (size_t)k * TSTR,
                il2b + (size_t)k * H, il2wt + (size_t)k * H * H,
                ilb + (size_t)k * H, ilwt + (size_t)k * H * H,
                nullptr, hb, nullptr, NA);
        }
    }
    // final: h2f = ssp(h@l1w+l1b)@l2w+l2b
    final_pair<<<NG, 256, 0, stream>>>(hb, l1b, l1wt, l2b, l2wt, h2f, NA);

    hipMemsetAsync(ms, 0, (size_t)NM * 4, stream);
    hipMemsetAsync(me, 0, (size_t)NM * 4, stream);
    mol_bounds<<<(NA + 255) / 256, 256, 0, stream>>>(a2c, c2m, ms, me);
    mol_sum<<<NM, 512, 0, stream>>>(ms, me, h2f, mol);
    final_mlp<<<NM, 64, 0, stream>>>(mol, h1w, h1b, h2w, h2b, out);
}